// Round 12
// baseline (300.912 us; speedup 1.0000x reference)
//
#include <hip/hip_runtime.h>
#include <hip/hip_bf16.h>
#include <math.h>

// Problem constants
#define BB 2
#define NN 2048
#define DM 1024
#define NH 16
#define NKV 4
#define HD 64
#define RR 256
#define HALF 1024
#define NM 1792   // NN - RR
#define NT 28     // key tiles of 64
#define NSPL 4    // attention split-K

typedef __bf16 bf16x8 __attribute__((ext_vector_type(8)));
typedef float f32x4 __attribute__((ext_vector_type(4)));

__device__ inline unsigned pk2(float a, float b) {
  union { __bf16 h; unsigned short u; } ua, ub;
  ua.h = (__bf16)a;
  ub.h = (__bf16)b;
  return (unsigned)ua.u | ((unsigned)ub.u << 16);
}

__device__ inline unsigned shu(unsigned v, int s) {
  return (unsigned)__shfl((int)v, s, 64);
}

// Async global->LDS, 16B per lane. LDS dest = wave-uniform base + lane*16.
__device__ __forceinline__ void async16(const void* g, void* l) {
  __builtin_amdgcn_global_load_lds(
      (const __attribute__((address_space(1))) void*)g,
      (__attribute__((address_space(3))) void*)l, 16, 0, 0);
}

// ---------------------------------------------------------------------------
// bf16 MFMA GEMM: C[M x N] = A[M x K] @ Bt[N x K]^T.  Block tile 128x64,
// wave tile 32x64. Fragment-linear LDS; staging via global_load_lds (16B).
// ---------------------------------------------------------------------------
__global__ __launch_bounds__(256) void gemm_bf16(
    const __bf16* __restrict__ A, const __bf16* __restrict__ Bt,
    float* __restrict__ C, int M, int N, int K) {
  __shared__ __align__(16) __bf16 As[8192];  // 128 x 64
  __shared__ __align__(16) __bf16 Bs[4096];  // 64 x 64
  const int bm0 = blockIdx.x * 128;
  const int bn0 = blockIdx.y * 64;
  const int w = threadIdx.x >> 6;
  const int lane = threadIdx.x & 63;
  f32x4 acc[2][4];
#pragma unroll
  for (int i = 0; i < 2; ++i)
#pragma unroll
    for (int nt = 0; nt < 4; ++nt) acc[i][nt] = (f32x4){0.f, 0.f, 0.f, 0.f};
  for (int kk = 0; kk < K; kk += 64) {
    __syncthreads();
#pragma unroll
    for (int it = 0; it < 4; ++it) {
      const int c = it * 256 + w * 64 + lane;
      async16(A + (size_t)(bm0 + ((c >> 7) << 4) + (c & 15)) * K + kk +
                  (((c >> 6) & 1) << 5) + (((c >> 4) & 3) << 3),
              &As[(it * 256 + w * 64) * 8]);
    }
#pragma unroll
    for (int it = 0; it < 2; ++it) {
      const int c = it * 256 + w * 64 + lane;
      async16(Bt + (size_t)(bn0 + ((c >> 7) << 4) + (c & 15)) * K + kk +
                  (((c >> 6) & 1) << 5) + (((c >> 4) & 3) << 3),
              &Bs[(it * 256 + w * 64) * 8]);
    }
    __syncthreads();
#pragma unroll
    for (int s = 0; s < 2; ++s) {
      bf16x8 a0 = *(const bf16x8*)&As[((2 * w) * 128 + s * 64 + lane) * 8];
      bf16x8 a1 = *(const bf16x8*)&As[((2 * w + 1) * 128 + s * 64 + lane) * 8];
#pragma unroll
      for (int nt = 0; nt < 4; ++nt) {
        bf16x8 bfr = *(const bf16x8*)&Bs[(nt * 128 + s * 64 + lane) * 8];
        acc[0][nt] =
            __builtin_amdgcn_mfma_f32_16x16x32_bf16(a0, bfr, acc[0][nt], 0, 0, 0);
        acc[1][nt] =
            __builtin_amdgcn_mfma_f32_16x16x32_bf16(a1, bfr, acc[1][nt], 0, 0, 0);
      }
    }
  }
  const int g = lane >> 4, ml = lane & 15;
#pragma unroll
  for (int i = 0; i < 2; ++i)
#pragma unroll
    for (int nt = 0; nt < 4; ++nt)
#pragma unroll
      for (int r = 0; r < 4; ++r)
        C[(size_t)(bm0 + (2 * w + i) * 16 + g * 4 + r) * N + bn0 + nt * 16 +
          ml] = acc[i][nt][r];
}

// ---------------------------------------------------------------------------
// Wo GEMM (128x64 tiles, async staging) with fused unmerge-scatter epilogue.
// ---------------------------------------------------------------------------
__global__ __launch_bounds__(256) void gemm_wo(
    const __bf16* __restrict__ A, const __bf16* __restrict__ Bt,
    const int* __restrict__ keep_idx, const int* __restrict__ dst2,
    float* __restrict__ out, int M, int N, int K) {
  __shared__ __align__(16) __bf16 As[8192];
  __shared__ __align__(16) __bf16 Bs[4096];
  const int bm0 = blockIdx.x * 128;
  const int bn0 = blockIdx.y * 64;
  const int w = threadIdx.x >> 6;
  const int lane = threadIdx.x & 63;
  f32x4 acc[2][4];
#pragma unroll
  for (int i = 0; i < 2; ++i)
#pragma unroll
    for (int nt = 0; nt < 4; ++nt) acc[i][nt] = (f32x4){0.f, 0.f, 0.f, 0.f};
  for (int kk = 0; kk < K; kk += 64) {
    __syncthreads();
#pragma unroll
    for (int it = 0; it < 4; ++it) {
      const int c = it * 256 + w * 64 + lane;
      async16(A + (size_t)(bm0 + ((c >> 7) << 4) + (c & 15)) * K + kk +
                  (((c >> 6) & 1) << 5) + (((c >> 4) & 3) << 3),
              &As[(it * 256 + w * 64) * 8]);
    }
#pragma unroll
    for (int it = 0; it < 2; ++it) {
      const int c = it * 256 + w * 64 + lane;
      async16(Bt + (size_t)(bn0 + ((c >> 7) << 4) + (c & 15)) * K + kk +
                  (((c >> 6) & 1) << 5) + (((c >> 4) & 3) << 3),
              &Bs[(it * 256 + w * 64) * 8]);
    }
    __syncthreads();
#pragma unroll
    for (int s = 0; s < 2; ++s) {
      bf16x8 a0 = *(const bf16x8*)&As[((2 * w) * 128 + s * 64 + lane) * 8];
      bf16x8 a1 = *(const bf16x8*)&As[((2 * w + 1) * 128 + s * 64 + lane) * 8];
#pragma unroll
      for (int nt = 0; nt < 4; ++nt) {
        bf16x8 bfr = *(const bf16x8*)&Bs[(nt * 128 + s * 64 + lane) * 8];
        acc[0][nt] =
            __builtin_amdgcn_mfma_f32_16x16x32_bf16(a0, bfr, acc[0][nt], 0, 0, 0);
        acc[1][nt] =
            __builtin_amdgcn_mfma_f32_16x16x32_bf16(a1, bfr, acc[1][nt], 0, 0, 0);
      }
    }
  }
  const int g = lane >> 4, ml = lane & 15;
#pragma unroll
  for (int i = 0; i < 2; ++i)
#pragma unroll
    for (int r = 0; r < 4; ++r) {
      const int row = bm0 + (2 * w + i) * 16 + g * 4 + r;
      const int bb = row / NM, tt = row % NM;
      const int p1 = keep_idx[bb * NM + tt];
      const int p2 = dst2[bb * NM + tt];
#pragma unroll
      for (int nt = 0; nt < 4; ++nt) {
        const int col = bn0 + nt * 16 + ml;
        float v = acc[i][nt][r];
        out[((size_t)(bb * NN + p1)) * DM + col] = v;
        if (p2 >= 0) out[((size_t)(bb * NN + p2)) * DM + col] = v;
      }
    }
}

// ---------------------------------------------------------------------------
// 3-term hi/lo MFMA GEMM (fp32-accurate), async staging, 64x64 tiles.
// Split-K via blockIdx.z (separate outputs C0/C1).
// ---------------------------------------------------------------------------
__global__ __launch_bounds__(256) void gemm3t(
    const __bf16* __restrict__ Ah, const __bf16* __restrict__ Al,
    const __bf16* __restrict__ Bh, const __bf16* __restrict__ Bl,
    float* __restrict__ C0, float* __restrict__ C1, int M, int N, int K) {
  __shared__ __align__(16) __bf16 Ahs[4096], Als[4096], Bhs[4096], Bls[4096];
  const int z = blockIdx.z;
  float* C = z ? C1 : C0;
  const int kof = z * (K / 2);
  const int bm0 = blockIdx.x * 64;
  const int bn0 = blockIdx.y * 64;
  const int w = threadIdx.x >> 6;
  const int lane = threadIdx.x & 63;
  f32x4 acc[4];
#pragma unroll
  for (int nt = 0; nt < 4; ++nt) acc[nt] = (f32x4){0.f, 0.f, 0.f, 0.f};
  for (int kk = kof; kk < kof + K / 2; kk += 64) {
    __syncthreads();
#pragma unroll
    for (int it = 0; it < 2; ++it) {
      const int c = it * 256 + w * 64 + lane;
      const size_t ra = (size_t)(bm0 + ((c >> 7) << 4) + (c & 15)) * K;
      const size_t rb = (size_t)(bn0 + ((c >> 7) << 4) + (c & 15)) * K;
      const int col = kk + (((c >> 6) & 1) << 5) + (((c >> 4) & 3) << 3);
      const int lb = (it * 256 + w * 64) * 8;
      async16(Ah + ra + col, &Ahs[lb]);
      async16(Al + ra + col, &Als[lb]);
      async16(Bh + rb + col, &Bhs[lb]);
      async16(Bl + rb + col, &Bls[lb]);
    }
    __syncthreads();
#pragma unroll
    for (int s = 0; s < 2; ++s) {
      bf16x8 ah = *(const bf16x8*)&Ahs[((w * 2 + s) * 64 + lane) * 8];
      bf16x8 al = *(const bf16x8*)&Als[((w * 2 + s) * 64 + lane) * 8];
#pragma unroll
      for (int nt = 0; nt < 4; ++nt) {
        bf16x8 bh = *(const bf16x8*)&Bhs[((nt * 2 + s) * 64 + lane) * 8];
        bf16x8 bl = *(const bf16x8*)&Bls[((nt * 2 + s) * 64 + lane) * 8];
        acc[nt] = __builtin_amdgcn_mfma_f32_16x16x32_bf16(al, bh, acc[nt], 0, 0, 0);
        acc[nt] = __builtin_amdgcn_mfma_f32_16x16x32_bf16(ah, bl, acc[nt], 0, 0, 0);
        acc[nt] = __builtin_amdgcn_mfma_f32_16x16x32_bf16(ah, bh, acc[nt], 0, 0, 0);
      }
    }
  }
  const int g = lane >> 4, ml = lane & 15;
#pragma unroll
  for (int nt = 0; nt < 4; ++nt)
#pragma unroll
    for (int r = 0; r < 4; ++r)
      C[(size_t)(bm0 + w * 16 + g * 4 + r) * N + bn0 + nt * 16 + ml] =
          acc[nt][r];
}

// ---------------------------------------------------------------------------
// Scores 3-term GEMM with fused per-tile row-argmax epilogue (async staging).
// ---------------------------------------------------------------------------
__global__ __launch_bounds__(256) void gemm_scam(
    const __bf16* __restrict__ Ah, const __bf16* __restrict__ Al,
    const __bf16* __restrict__ Bh, const __bf16* __restrict__ Bl,
    float* __restrict__ sval, int* __restrict__ sidx) {
  __shared__ __align__(16) __bf16 Ahs[4096], Als[4096], Bhs[4096], Bls[4096];
  const size_t zo = (size_t)blockIdx.z * HALF * 256;
  const int bm0 = blockIdx.x * 64;
  const int bn0 = blockIdx.y * 64;
  const int w = threadIdx.x >> 6;
  const int lane = threadIdx.x & 63;
  f32x4 acc[4];
#pragma unroll
  for (int nt = 0; nt < 4; ++nt) acc[nt] = (f32x4){0.f, 0.f, 0.f, 0.f};
  for (int kk = 0; kk < 256; kk += 64) {
    __syncthreads();
#pragma unroll
    for (int it = 0; it < 2; ++it) {
      const int c = it * 256 + w * 64 + lane;
      const size_t ra = zo + (size_t)(bm0 + ((c >> 7) << 4) + (c & 15)) * 256;
      const size_t rb = zo + (size_t)(bn0 + ((c >> 7) << 4) + (c & 15)) * 256;
      const int col = kk + (((c >> 6) & 1) << 5) + (((c >> 4) & 3) << 3);
      const int lb = (it * 256 + w * 64) * 8;
      async16(Ah + ra + col, &Ahs[lb]);
      async16(Al + ra + col, &Als[lb]);
      async16(Bh + rb + col, &Bhs[lb]);
      async16(Bl + rb + col, &Bls[lb]);
    }
    __syncthreads();
#pragma unroll
    for (int s = 0; s < 2; ++s) {
      bf16x8 ah = *(const bf16x8*)&Ahs[((w * 2 + s) * 64 + lane) * 8];
      bf16x8 al = *(const bf16x8*)&Als[((w * 2 + s) * 64 + lane) * 8];
#pragma unroll
      for (int nt = 0; nt < 4; ++nt) {
        bf16x8 bh = *(const bf16x8*)&Bhs[((nt * 2 + s) * 64 + lane) * 8];
        bf16x8 bl = *(const bf16x8*)&Bls[((nt * 2 + s) * 64 + lane) * 8];
        acc[nt] = __builtin_amdgcn_mfma_f32_16x16x32_bf16(al, bh, acc[nt], 0, 0, 0);
        acc[nt] = __builtin_amdgcn_mfma_f32_16x16x32_bf16(ah, bl, acc[nt], 0, 0, 0);
        acc[nt] = __builtin_amdgcn_mfma_f32_16x16x32_bf16(ah, bh, acc[nt], 0, 0, 0);
      }
    }
  }
  const int g = lane >> 4, ml = lane & 15;
#pragma unroll
  for (int r = 0; r < 4; ++r) {
    float bv = acc[0][r];
    int bc = bn0 + ml;
#pragma unroll
    for (int nt = 1; nt < 4; ++nt) {
      float v = acc[nt][r];
      int c = bn0 + nt * 16 + ml;
      if (v > bv) { bv = v; bc = c; }
    }
#pragma unroll
    for (int off = 1; off < 16; off <<= 1) {
      float vo = __shfl_xor(bv, off, 64);
      int co = __shfl_xor(bc, off, 64);
      if (vo > bv || (vo == bv && co < bc)) { bv = vo; bc = co; }
    }
    if (ml == 0) {
      const int row = bm0 + w * 16 + g * 4 + r;
      const size_t o = ((size_t)blockIdx.z * HALF + row) * 16 + (bn0 >> 6);
      sval[o] = bv;
      sidx[o] = bc;
    }
  }
}

// ---------------------------------------------------------------------------
// Fused input prep: z<640 -> weight transposes; z>=640 -> x hi/lo split.
// ---------------------------------------------------------------------------
__global__ __launch_bounds__(256) void prep_in(
    const float* __restrict__ Wq, const float* __restrict__ Wk,
    const float* __restrict__ Wv, const float* __restrict__ Wo,
    const float* __restrict__ x, __bf16* __restrict__ Wqkvt,
    __bf16* __restrict__ Wktl, __bf16* __restrict__ Wot,
    __bf16* __restrict__ xh, __bf16* __restrict__ xl) {
  const int z = blockIdx.x;
  if (z >= 640) {
    const int i = (z - 640) * 256 + threadIdx.x;
    float4 v = ((const float4*)x)[i];
    float f[4] = {v.x, v.y, v.z, v.w};
    union { __bf16 h[4]; uint2 u; } H, L;
#pragma unroll
    for (int j = 0; j < 4; ++j) {
      __bf16 hh = (__bf16)f[j];
      H.h[j] = hh;
      L.h[j] = (__bf16)(f[j] - (float)hh);
    }
    ((uint2*)xh)[i] = H.u;
    ((uint2*)xl)[i] = L.u;
    return;
  }
  __shared__ float ld[64][65];
  const float* src;
  __bf16* dsth;
  __bf16* dstl = nullptr;
  int N, k0, n0, rowoff;
  if (z < 256) {
    src = Wq; N = 1024; k0 = (z >> 4) << 6; n0 = (z & 15) << 6;
    dsth = Wqkvt; rowoff = 0;
  } else if (z < 320) {
    int zz = z - 256;
    src = Wk; N = 256; k0 = (zz >> 2) << 6; n0 = (zz & 3) << 6;
    dsth = Wqkvt; rowoff = 1024; dstl = Wktl;
  } else if (z < 384) {
    int zz = z - 320;
    src = Wv; N = 256; k0 = (zz >> 2) << 6; n0 = (zz & 3) << 6;
    dsth = Wqkvt; rowoff = 1280;
  } else {
    int zz = z - 384;
    src = Wo; N = 1024; k0 = (zz >> 4) << 6; n0 = (zz & 15) << 6;
    dsth = Wot; rowoff = 0;
  }
  for (int i = threadIdx.x; i < 1024; i += 256) {
    int r = i >> 4, c4 = i & 15;
    float4 v = *(const float4*)(src + (size_t)(k0 + r) * N + n0 + c4 * 4);
    ld[r][c4 * 4 + 0] = v.x;
    ld[r][c4 * 4 + 1] = v.y;
    ld[r][c4 * 4 + 2] = v.z;
    ld[r][c4 * 4 + 3] = v.w;
  }
  __syncthreads();
  for (int i = threadIdx.x; i < 4096; i += 256) {
    int n = i >> 6, k = i & 63;
    float v = ld[k][n];
    __bf16 hh = (__bf16)v;
    dsth[(size_t)(rowoff + n0 + n) * 1024 + k0 + k] = hh;
    if (dstl)
      dstl[(size_t)(n0 + n) * 1024 + k0 + k] = (__bf16)(v - (float)hh);
  }
}

// ---------------------------------------------------------------------------
// Normalize metric rows (sum of split-K halves); write bf16 hi/lo.
// ---------------------------------------------------------------------------
__global__ __launch_bounds__(256) void normalize_split(
    const float* __restrict__ m0, const float* __restrict__ m1,
    __bf16* __restrict__ anh, __bf16* __restrict__ anl,
    __bf16* __restrict__ bnh, __bf16* __restrict__ bnl) {
  const int row = blockIdx.x;
  const int b = row >> 11;
  const int r = row & 2047;
  const int t = threadIdx.x;
  float v = m0[(size_t)row * 256 + t] + m1[(size_t)row * 256 + t];
  float ss = v * v;
#pragma unroll
  for (int o = 32; o > 0; o >>= 1) ss += __shfl_xor(ss, o, 64);
  __shared__ float wsum[4];
  if ((t & 63) == 0) wsum[t >> 6] = ss;
  __syncthreads();
  float tot = wsum[0] + wsum[1] + wsum[2] + wsum[3];
  float inv = 1.f / fmaxf(sqrtf(tot), 1e-12f);
  float nv = v * inv;
  __bf16 hh = (__bf16)nv;
  __bf16 ll = (__bf16)(nv - (float)hh);
  size_t o = ((size_t)b * HALF + (r >> 1)) * 256 + t;
  if (r & 1) {
    bnh[o] = hh;
    bnl[o] = ll;
  } else {
    anh[o] = hh;
    anl[o] = ll;
  }
}

// ---------------------------------------------------------------------------
// Fused: reduce 16 argmax partials per row (-> best_b) + stable descending
// bitonic argsort of the 1024 best scores per batch. 512 threads.
// ---------------------------------------------------------------------------
__global__ __launch_bounds__(512) void sort_desc(
    const float* __restrict__ sval, const int* __restrict__ sidx,
    int* __restrict__ best_b, int* __restrict__ order) {
  const int b = blockIdx.x;
  __shared__ float sv[1024];
  __shared__ int si[1024];
  for (int i = threadIdx.x; i < 1024; i += 512) {
    const size_t base = ((size_t)b * HALF + i) * 16;
    float bv = sval[base];
    int bc = sidx[base];
#pragma unroll
    for (int e = 1; e < 16; ++e) {
      float v = sval[base + e];
      int c = sidx[base + e];
      if (v > bv || (v == bv && c < bc)) { bv = v; bc = c; }
    }
    sv[i] = bv;
    si[i] = i;
    best_b[b * HALF + i] = bc;
  }
  __syncthreads();
  for (int k = 2; k <= 1024; k <<= 1) {
    for (int j = k >> 1; j > 0; j >>= 1) {
      for (int t = threadIdx.x; t < 1024; t += 512) {
        int ixj = t ^ j;
        if (ixj > t) {
          bool dir = ((t & k) == 0);
          float va = sv[t], vb = sv[ixj];
          int ia = si[t], ib = si[ixj];
          bool before = (vb > va) || (vb == va && ib < ia);
          if (before == dir) {
            sv[t] = vb; sv[ixj] = va;
            si[t] = ib; si[ixj] = ia;
          }
        }
      }
      __syncthreads();
    }
  }
  for (int i = threadIdx.x; i < 1024; i += 512) order[b * HALF + i] = si[i];
}

// ---------------------------------------------------------------------------
// Parallel greedy selection (exact serial-scan equivalent) + index maps.
// ---------------------------------------------------------------------------
__global__ __launch_bounds__(256) void select_and_index(
    const int* __restrict__ best_b, const int* __restrict__ order,
    int* __restrict__ keep_idx, int* __restrict__ partner,
    int* __restrict__ dst2) {
  const int b = blockIdx.x;
  __shared__ int rankA[HALF];
  __shared__ int minrank[HALF];
  __shared__ int taken[HALF];
  __shared__ int sel_a[RR], sel_b[RR];
  __shared__ int removed[NN];
  __shared__ int src_row[NN];
  __shared__ int tsum[256];
  const int t = threadIdx.x;

  for (int i = t; i < HALF; i += 256) { minrank[i] = 0x7fffffff; taken[i] = 0; }
  for (int i = t; i < NN; i += 256) {
    removed[i] = 0;
    partner[b * NN + i] = -1;
  }
  for (int i = t; i < NM; i += 256) dst2[b * NM + i] = -1;
  __syncthreads();
  int ord[4];
#pragma unroll
  for (int q = 0; q < 4; ++q) {
    int step = t * 4 + q;
    ord[q] = order[b * HALF + step];
    rankA[ord[q]] = step;
  }
  __syncthreads();
#pragma unroll
  for (int q = 0; q < 4; ++q) {
    int a = t * 4 + q;
    atomicMin(&minrank[best_b[b * HALF + a]], rankA[a]);
  }
  __syncthreads();
  for (int i = t; i < HALF; i += 256) {
    int mr = minrank[i];
    if (mr != 0x7fffffff) taken[mr] = 1;
  }
  __syncthreads();
  int c[4];
  int mysum = 0;
#pragma unroll
  for (int q = 0; q < 4; ++q) { c[q] = taken[t * 4 + q]; mysum += c[q]; }
  tsum[t] = mysum;
  __syncthreads();
  for (int off = 1; off < 256; off <<= 1) {
    int v = (t >= off) ? tsum[t - off] : 0;
    __syncthreads();
    tsum[t] += v;
    __syncthreads();
  }
  int run = tsum[t] - mysum;
#pragma unroll
  for (int q = 0; q < 4; ++q) {
    if (c[q] && run < RR) {
      int a = ord[q];
      sel_a[run] = 2 * a;
      sel_b[run] = 2 * best_b[b * HALF + a] + 1;
    }
    run += c[q];
  }
  __syncthreads();
  const int cnt = min(tsum[255], RR);
  if (t >= cnt) { sel_a[t] = sel_a[0]; sel_b[t] = sel_b[0]; }
  __syncthreads();
  {
    int ga = sel_a[t], gb = sel_b[t];
    removed[gb] = 1;
    partner[b * NN + ga] = gb;
  }
  __syncthreads();
  int myc = 0;
#pragma unroll
  for (int q = 0; q < 8; ++q) myc += !removed[8 * t + q];
  tsum[t] = myc;
  __syncthreads();
  for (int off = 1; off < 256; off <<= 1) {
    int v = (t >= off) ? tsum[t - off] : 0;
    __syncthreads();
    tsum[t] += v;
    __syncthreads();
  }
  int pos = tsum[t] - myc;
#pragma unroll
  for (int q = 0; q < 8; ++q) {
    int p = 8 * t + q;
    int sr = -1;
    if (!removed[p]) {
      if (pos < NM) {
        keep_idx[b * NM + pos] = p;
        sr = pos;
      }
      ++pos;
    }
    src_row[p] = sr;
  }
  __syncthreads();
  {
    int sr = src_row[sel_a[t]];
    dst2[b * NM + sr] = sel_b[t];
  }
}

// ---------------------------------------------------------------------------
// Merge -> bf16 x_mb
// ---------------------------------------------------------------------------
__global__ __launch_bounds__(256) void merge_kernel(
    const float* __restrict__ x, const int* __restrict__ keep_idx,
    const int* __restrict__ partner, __bf16* __restrict__ x_mb) {
  const int mrow = blockIdx.x;
  const int b = mrow / NM;
  const int t = mrow % NM;
  const int p = keep_idx[b * NM + t];
  const int pp = partner[b * NN + p];
  const float4* src =
      reinterpret_cast<const float4*>(x + ((size_t)b * NN + p) * DM);
  float4 val = src[threadIdx.x];
  if (pp >= 0) {
    const float4* s2 =
        reinterpret_cast<const float4*>(x + ((size_t)b * NN + pp) * DM);
    float4 v2 = s2[threadIdx.x];
    val.x = 0.5f * (val.x + v2.x);
    val.y = 0.5f * (val.y + v2.y);
    val.z = 0.5f * (val.z + v2.z);
    val.w = 0.5f * (val.w + v2.w);
  }
  union { __bf16 h[4]; uint2 u; } U;
  U.h[0] = (__bf16)val.x;
  U.h[1] = (__bf16)val.y;
  U.h[2] = (__bf16)val.z;
  U.h[3] = (__bf16)val.w;
  ((uint2*)(x_mb + (size_t)mrow * DM))[threadIdx.x] = U.u;
}

// ---------------------------------------------------------------------------
// Fused QKV post-processing: z < BB*NM -> RoPE q+k repack; else V transpose.
// ---------------------------------------------------------------------------
__global__ __launch_bounds__(256) void prep_qkv(
    const float* __restrict__ qkv, const float* __restrict__ fc,
    __bf16* __restrict__ qbh, __bf16* __restrict__ kbh,
    __bf16* __restrict__ vtb) {
  __shared__ float ld[64][65];
  const int z = blockIdx.x;
  if (z < BB * NM) {
    const int row = z;
    const int t = row % NM;
    const int b = row / NM;
    for (int idx = threadIdx.x; idx < 640; idx += 256) {
      int u = idx & 31;
      float c = fc[(t * 32 + u) * 2];
      float s = fc[(t * 32 + u) * 2 + 1];
      if (idx < 512) {
        int h = idx >> 5;
        const float* p = qkv + (size_t)row * 1536 + h * 64 + 2 * u;
        float x1 = p[0], x2 = p[1];
        __bf16* d = qbh + ((size_t)(b * NH + h) * NM + t) * 64 + 2 * u;
        d[0] = (__bf16)((x1 * c - x2 * s) * 0.125f);
        d[1] = (__bf16)((x1 * s + x2 * c) * 0.125f);
      } else {
        int h = (idx - 512) >> 5;
        const float* p = qkv + (size_t)row * 1536 + 1024 + h * 64 + 2 * u;
        float x1 = p[0], x2 = p[1];
        __bf16* d = kbh + ((size_t)(b * NKV + h) * NM + t) * 64 + 2 * u;
        d[0] = (__bf16)(x1 * c - x2 * s);
        d[1] = (__bf16)(x1 * s + x2 * c);
      }
    }
    return;
  }
  int bid = z - BB * NM;
  const int kt = bid % (NM / 64); bid /= (NM / 64);
  const int kvh = bid % NKV;
  const int b = bid / NKV;
  const int j0 = kt * 64;
  for (int t2 = threadIdx.x; t2 < 1024; t2 += 256) {
    int key = t2 >> 4, c4 = t2 & 15;
    float4 v4 = *reinterpret_cast<const float4*>(
        qkv + (size_t)(b * NM + j0 + key) * 1536 + 1280 + kvh * 64 + c4 * 4);
    ld[key][c4 * 4 + 0] = v4.x;
    ld[key][c4 * 4 + 1] = v4.y;
    ld[key][c4 * 4 + 2] = v4.z;
    ld[key][c4 * 4 + 3] = v4.w;
  }
  __syncthreads();
  const int dim = threadIdx.x >> 2, kc = threadIdx.x & 3;
  __bf16* out = vtb + ((size_t)(b * NKV + kvh) * 64 + dim) * NM + j0 + kc * 16;
#pragma unroll
  for (int kk = 0; kk < 16; ++kk) out[kk] = (__bf16)ld[kc * 16 + kk][dim];
}

// ---------------------------------------------------------------------------
// Flash attention, bf16 MFMA, S^T orientation, fixed-shift softmax,
// split-K over NSPL=4. 256-thread blocks (4 waves = 4 GQA heads x 1 q-tile):
// 8 resident blocks/CU -> 8 independent barrier groups hide staging drains.
// Single-buffer async K/V staging (16B global_load_lds).
// ---------------------------------------------------------------------------
__global__ __launch_bounds__(256) void attn_mfma(
    const __bf16* __restrict__ qbh, const __bf16* __restrict__ kbh,
    const __bf16* __restrict__ vtb, float* __restrict__ pl,
    __bf16* __restrict__ pacc) {
  __shared__ __align__(16) __bf16 Ks[4096];
  __shared__ __align__(16) __bf16 Vs[4096];
  int bid = blockIdx.x;
  const int qt1 = bid % (NM / 16); bid /= (NM / 16);
  const int split = bid % NSPL; bid /= NSPL;
  const int kvh = bid % NKV;
  const int b = bid / NKV;
  const int w = threadIdx.x >> 6;
  const int lane = threadIdx.x & 63;
  const int h = kvh * 4 + w;
  const int qt = qt1 * 16;
  const int g = lane >> 4;
  const int ml = lane & 15;

  const __bf16* qrow = qbh + ((size_t)(b * NH + h) * NM + qt + ml) * 64;
  bf16x8 qa0 = *reinterpret_cast<const bf16x8*>(qrow + g * 8);
  bf16x8 qa1 = *reinterpret_cast<const bf16x8*>(qrow + 32 + g * 8);

  f32x4 acc[4];
#pragma unroll
  for (int mt = 0; mt < 4; ++mt) acc[mt] = (f32x4){0.f, 0.f, 0.f, 0.f};
  float lsum = 0.f;

  const __bf16* kp = kbh + (size_t)(b * NKV + kvh) * NM * 64;
  const __bf16* vp = vtb + (size_t)(b * NKV + kvh) * 64 * NM;
  const int src0 = ((lane >> 4) & 1) * 32 + ml;
  const int src1 = src0 + 16;
  const int sel = g >> 1;

  const int jt0 = split * (NT / NSPL);
  for (int jt = jt0; jt < jt0 + NT / NSPL; ++jt) {
    __syncthreads();
#pragma unroll
    for (int it = 0; it < 2; ++it) {
      const int c = it * 256 + w * 64 + lane;
      const int lb = (it * 256 + w * 64) * 8;
      async16(kp + (size_t)(jt * 64 + ((c >> 7) << 4) + (c & 15)) * 64 +
                  (((c >> 6) & 1) << 5) + (((c >> 4) & 3) << 3),
              &Ks[lb]);
      async16(vp + (size_t)(((c >> 7) << 4) + (c & 15)) * NM + jt * 64 +
                  (((c >> 6) & 1) << 5) + (((c >> 4) & 3) << 3),
              &Vs[lb]);
    }
    __syncthreads();
    f32x4 S[4];
#pragma unroll
    for (int nt = 0; nt < 4; ++nt) {
      bf16x8 k0 = *(const bf16x8*)&Ks[(nt * 128 + lane) * 8];
      bf16x8 k1 = *(const bf16x8*)&Ks[(nt * 128 + 64 + lane) * 8];
      f32x4 s4 = (f32x4){0.f, 0.f, 0.f, 0.f};
      s4 = __builtin_amdgcn_mfma_f32_16x16x32_bf16(k0, qa0, s4, 0, 0, 0);
      s4 = __builtin_amdgcn_mfma_f32_16x16x32_bf16(k1, qa1, s4, 0, 0, 0);
      S[nt] = s4;
    }
    float p[4][4];
#pragma unroll
    for (int nt = 0; nt < 4; ++nt)
#pragma unroll
      for (int r = 0; r < 4; ++r) {
        p[nt][r] = __expf(S[nt][r]);
        lsum += p[nt][r];
      }
    unsigned pk[4][2];
#pragma unroll
    for (int nt = 0; nt < 4; ++nt) {
      pk[nt][0] = pk2(p[nt][0], p[nt][1]);
      pk[nt][1] = pk2(p[nt][2], p[nt][3]);
    }
    unsigned A00 = shu(pk[0][0], src0), A01 = shu(pk[0][1], src0);
    unsigned A10 = shu(pk[1][0], src0), A11 = shu(pk[1][1], src0);
    unsigned B00 = shu(pk[0][0], src1), B01 = shu(pk[0][1], src1);
    unsigned B10 = shu(pk[1][0], src1), B11 = shu(pk[1][1], src1);
    unsigned C00 = shu(pk[2][0], src0), C01 = shu(pk[2][1], src0);
    unsigned C10 = shu(pk[3][0], src0), C11 = shu(pk[3][1], src0);
    unsigned D00 = shu(pk[2][0], src1), D01 = shu(pk[2][1], src1);
    unsigned D10 = shu(pk[3][0], src1), D11 = shu(pk[3][1], src1);
    union { uint4 u; bf16x8 v; } P0, P1;
    P0.u.x = sel ? A10 : A00; P0.u.y = sel ? A11 : A01;
    P0.u.z = sel ? B10 : B00; P0.u.w = sel ? B11 : B01;
    P1.u.x = sel ? C10 : C00; P1.u.y = sel ? C11 : C01;
    P1.u.z = sel ? D10 : D00; P1.u.w = sel ? D11 : D01;
#pragma unroll
    for (int mt = 0; mt < 4; ++mt) {
      bf16x8 v0 = *(const bf16x8*)&Vs[(mt * 128 + lane) * 8];
      bf16x8 v1 = *(const bf16x8*)&Vs[(mt * 128 + 64 + lane) * 8];
      acc[mt] = __builtin_amdgcn_mfma_f32_16x16x32_bf16(v0, P0.v, acc[mt], 0, 0, 0);
      acc[mt] = __builtin_amdgcn_mfma_f32_16x16x32_bf16(v1, P1.v, acc[mt], 0, 0, 0);
    }
  }
  lsum += __shfl_xor(lsum, 16, 64);
  lsum += __shfl_xor(lsum, 32, 64);
  const size_t row = (size_t)(b * NH + h) * NM + qt + ml;
  if (g == 0) pl[row * NSPL + split] = lsum;
  __bf16* pa = pacc + (row * NSPL + split) * 64;
#pragma unroll
  for (int mt = 0; mt < 4; ++mt) {
    uint2 u;
    u.x = pk2(acc[mt][0], acc[mt][1]);
    u.y = pk2(acc[mt][2], acc[mt][3]);
    *reinterpret_cast<uint2*>(pa + mt * 16 + g * 4) = u;
  }
}

// ---------------------------------------------------------------------------
// Split-K combine (fixed shift: plain sums) -> bf16 attn_ob
// ---------------------------------------------------------------------------
__global__ __launch_bounds__(256) void attn_combine(
    const float* __restrict__ pl, const __bf16* __restrict__ pacc,
    __bf16* __restrict__ attn_ob) {
  const size_t rid = (size_t)blockIdx.x * 4 + (threadIdx.x >> 6);
  const int d = threadIdx.x & 63;
  float num = 0.f, den = 0.f;
#pragma unroll
  for (int s = 0; s < NSPL; ++s) {
    num += (float)pacc[(rid * NSPL + s) * 64 + d];
    den += pl[rid * NSPL + s];
  }
  float o = num / den;
  const int q = (int)(rid % NM);
  const int h = (int)((rid / NM) % NH);
  const int b = (int)(rid / ((size_t)NM * NH));
  attn_ob[((size_t)(b * NM + q)) * DM + h * 64 + d] = (__bf16)o;
}

// ---------------------------------------------------------------------------
extern "C" void kernel_launch(void* const* d_in, const int* in_sizes, int n_in,
                              void* d_out, int out_size, void* d_ws,
                              size_t ws_size, hipStream_t stream) {
  const float* x = (const float*)d_in[0];
  const float* fc = (const float*)d_in[1];
  const float* Wq = (const float*)d_in[2];
  const float* Wk = (const float*)d_in[3];
  const float* Wv = (const float*)d_in[4];
  const float* Wo = (const float*)d_in[5];
  float* out = (float*)d_out;

  char* ws = (char*)d_ws;
  size_t off = 0;
  auto alloc = [&](size_t bytes) {
    void* p = ws + off;
    off += (bytes + 255) & ~(size_t)255;
    return p;
  };
  float* metric0 = (float*)alloc((size_t)BB * NN * 256 * 4);
  float* metric1 = (float*)alloc((size_t)BB * NN * 256 * 4);
  int* best_b = (int*)alloc((size_t)BB * HALF * 4);
  int* order = (int*)alloc((size_t)BB * HALF * 4);
  int* keep_idx = (int*)alloc((size_t)BB * NM * 4);
  int* partner = (int*)alloc((size_t)BB * NN * 4);
  int* dst2 = (int*)alloc((size_t)BB * NM * 4);
  float* sval = (float*)alloc((size_t)BB * HALF * 16 * 4);
  int* sidx = (int*)alloc((size_t)BB * HALF * 16 * 4);
  char* bigreg = (char*)alloc((size_t)30 * 1024 * 1024);
  __bf16* xh = (__bf16*)bigreg;
  __bf16* xl = (__bf16*)(bigreg + (size_t)8704 * 1024);
  __bf16* anh = (__bf16*)bigreg;
  __bf16* anl = (__bf16*)(bigreg + (size_t)1100 * 1024);
  __bf16* bnh = (__bf16*)(bigreg + (size_t)2200 * 1024);
  __bf16* bnl = (__bf16*)(bigreg + (size_t)3300 * 1024);
  float* qkv = (float*)bigreg;
  __bf16* pacc = (__bf16*)bigreg;
  __bf16* x_mb = (__bf16*)alloc((size_t)BB * NM * DM * 2);
  __bf16* qbh = (__bf16*)alloc((size_t)BB * NH * NM * 64 * 2);
  __bf16* kbh = (__bf16*)alloc((size_t)BB * NKV * NM * 64 * 2);
  __bf16* vtb = (__bf16*)alloc((size_t)BB * NKV * 64 * NM * 2);
  __bf16* attn_ob = (__bf16*)alloc((size_t)BB * NM * DM * 2);
  float* pl = (float*)alloc((size_t)BB * NH * NM * NSPL * 4);
  __bf16* Wqkvt = (__bf16*)alloc((size_t)1536 * DM * 2);
  __bf16* Wktl = (__bf16*)alloc((size_t)256 * DM * 2);
  __bf16* Wot = (__bf16*)alloc((size_t)DM * DM * 2);
  const __bf16* Wkth = Wqkvt + (size_t)1024 * 1024;

  // ---- fused prep: weight transposes + x hi/lo split
  prep_in<<<640 + (BB * NN * DM / 4) / 256, 256, 0, stream>>>(
      Wq, Wk, Wv, Wo, x, Wqkvt, Wktl, Wot, xh, xl);
  // ---- metric = x @ Wk (3-term hi/lo MFMA, split-K x2)
  gemm3t<<<dim3(64, 4, 2), 256, 0, stream>>>(xh, xl, Wkth, Wktl, metric0,
                                             metric1, BB * NN, 256, DM);
  normalize_split<<<BB * NN, 256, 0, stream>>>(metric0, metric1, anh, anl, bnh,
                                               bnl);
  gemm_scam<<<dim3(16, 16, 2), 256, 0, stream>>>(anh, anl, bnh, bnl, sval,
                                                 sidx);
  // ---- fused argmax-reduce + sort
  sort_desc<<<BB, 512, 0, stream>>>(sval, sidx, best_b, order);
  select_and_index<<<BB, 256, 0, stream>>>(best_b, order, keep_idx, partner,
                                           dst2);
  merge_kernel<<<BB * NM, 256, 0, stream>>>(x, keep_idx, partner, x_mb);
  // ---- fused QKV projection
  gemm_bf16<<<dim3(28, 24), 256, 0, stream>>>(x_mb, Wqkvt, qkv, BB * NM, 1536,
                                              DM);
  // ---- fused RoPE + V repack
  prep_qkv<<<BB * NM + BB * NKV * (NM / 64), 256, 0, stream>>>(qkv, fc, qbh,
                                                               kbh, vtb);
  // ---- attention (256-thr blocks, split-K x4) + combine
  attn_mfma<<<BB * NKV * NSPL * (NM / 16), 256, 0, stream>>>(qbh, kbh, vtb, pl,
                                                             pacc);
  attn_combine<<<(BB * NH * NM) / 4, 256, 0, stream>>>(pl, pacc, attn_ob);
  // ---- output projection with fused unmerge scatter
  gemm_wo<<<dim3(28, 16), 256, 0, stream>>>(attn_ob, Wot, keep_idx, dst2, out,
                                            BB * NM, DM, DM);
}

// Round 13
// 286.532 us; speedup vs baseline: 1.0502x; 1.0502x over previous
//
#include <hip/hip_runtime.h>
#include <hip/hip_bf16.h>
#include <math.h>

// Problem constants
#define BB 2
#define NN 2048
#define DM 1024
#define NH 16
#define NKV 4
#define HD 64
#define RR 256
#define HALF 1024
#define NM 1792   // NN - RR
#define NT 28     // key tiles of 64
#define NSPL 4    // attention split-K

typedef __bf16 bf16x8 __attribute__((ext_vector_type(8)));
typedef float f32x4 __attribute__((ext_vector_type(4)));

__device__ inline unsigned pk2(float a, float b) {
  union { __bf16 h; unsigned short u; } ua, ub;
  ua.h = (__bf16)a;
  ub.h = (__bf16)b;
  return (unsigned)ua.u | ((unsigned)ub.u << 16);
}

// Async global->LDS, 16B per lane. LDS dest = wave-uniform base + lane*16.
__device__ __forceinline__ void async16(const void* g, void* l) {
  __builtin_amdgcn_global_load_lds(
      (const __attribute__((address_space(1))) void*)g,
      (__attribute__((address_space(3))) void*)l, 16, 0, 0);
}

// ---------------------------------------------------------------------------
// bf16 MFMA GEMM: C[M x N] = A[M x K] @ Bt[N x K]^T.  Block tile 128x64,
// wave tile 32x64. Fragment-linear LDS; staging via global_load_lds (16B).
// ---------------------------------------------------------------------------
__global__ __launch_bounds__(256) void gemm_bf16(
    const __bf16* __restrict__ A, const __bf16* __restrict__ Bt,
    float* __restrict__ C, int M, int N, int K) {
  __shared__ __align__(16) __bf16 As[8192];  // 128 x 64
  __shared__ __align__(16) __bf16 Bs[4096];  // 64 x 64
  const int bm0 = blockIdx.x * 128;
  const int bn0 = blockIdx.y * 64;
  const int w = threadIdx.x >> 6;
  const int lane = threadIdx.x & 63;
  f32x4 acc[2][4];
#pragma unroll
  for (int i = 0; i < 2; ++i)
#pragma unroll
    for (int nt = 0; nt < 4; ++nt) acc[i][nt] = (f32x4){0.f, 0.f, 0.f, 0.f};
  for (int kk = 0; kk < K; kk += 64) {
    __syncthreads();
#pragma unroll
    for (int it = 0; it < 4; ++it) {
      const int c = it * 256 + w * 64 + lane;
      async16(A + (size_t)(bm0 + ((c >> 7) << 4) + (c & 15)) * K + kk +
                  (((c >> 6) & 1) << 5) + (((c >> 4) & 3) << 3),
              &As[(it * 256 + w * 64) * 8]);
    }
#pragma unroll
    for (int it = 0; it < 2; ++it) {
      const int c = it * 256 + w * 64 + lane;
      async16(Bt + (size_t)(bn0 + ((c >> 7) << 4) + (c & 15)) * K + kk +
                  (((c >> 6) & 1) << 5) + (((c >> 4) & 3) << 3),
              &Bs[(it * 256 + w * 64) * 8]);
    }
    __syncthreads();
#pragma unroll
    for (int s = 0; s < 2; ++s) {
      bf16x8 a0 = *(const bf16x8*)&As[((2 * w) * 128 + s * 64 + lane) * 8];
      bf16x8 a1 = *(const bf16x8*)&As[((2 * w + 1) * 128 + s * 64 + lane) * 8];
#pragma unroll
      for (int nt = 0; nt < 4; ++nt) {
        bf16x8 bfr = *(const bf16x8*)&Bs[(nt * 128 + s * 64 + lane) * 8];
        acc[0][nt] =
            __builtin_amdgcn_mfma_f32_16x16x32_bf16(a0, bfr, acc[0][nt], 0, 0, 0);
        acc[1][nt] =
            __builtin_amdgcn_mfma_f32_16x16x32_bf16(a1, bfr, acc[1][nt], 0, 0, 0);
      }
    }
  }
  const int g = lane >> 4, ml = lane & 15;
#pragma unroll
  for (int i = 0; i < 2; ++i)
#pragma unroll
    for (int nt = 0; nt < 4; ++nt)
#pragma unroll
      for (int r = 0; r < 4; ++r)
        C[(size_t)(bm0 + (2 * w + i) * 16 + g * 4 + r) * N + bn0 + nt * 16 +
          ml] = acc[i][nt][r];
}

// ---------------------------------------------------------------------------
// Wo GEMM (128x64 tiles, async staging) with fused unmerge-scatter epilogue.
// ---------------------------------------------------------------------------
__global__ __launch_bounds__(256) void gemm_wo(
    const __bf16* __restrict__ A, const __bf16* __restrict__ Bt,
    const int* __restrict__ keep_idx, const int* __restrict__ dst2,
    float* __restrict__ out, int M, int N, int K) {
  __shared__ __align__(16) __bf16 As[8192];
  __shared__ __align__(16) __bf16 Bs[4096];
  const int bm0 = blockIdx.x * 128;
  const int bn0 = blockIdx.y * 64;
  const int w = threadIdx.x >> 6;
  const int lane = threadIdx.x & 63;
  f32x4 acc[2][4];
#pragma unroll
  for (int i = 0; i < 2; ++i)
#pragma unroll
    for (int nt = 0; nt < 4; ++nt) acc[i][nt] = (f32x4){0.f, 0.f, 0.f, 0.f};
  for (int kk = 0; kk < K; kk += 64) {
    __syncthreads();
#pragma unroll
    for (int it = 0; it < 4; ++it) {
      const int c = it * 256 + w * 64 + lane;
      async16(A + (size_t)(bm0 + ((c >> 7) << 4) + (c & 15)) * K + kk +
                  (((c >> 6) & 1) << 5) + (((c >> 4) & 3) << 3),
              &As[(it * 256 + w * 64) * 8]);
    }
#pragma unroll
    for (int it = 0; it < 2; ++it) {
      const int c = it * 256 + w * 64 + lane;
      async16(Bt + (size_t)(bn0 + ((c >> 7) << 4) + (c & 15)) * K + kk +
                  (((c >> 6) & 1) << 5) + (((c >> 4) & 3) << 3),
              &Bs[(it * 256 + w * 64) * 8]);
    }
    __syncthreads();
#pragma unroll
    for (int s = 0; s < 2; ++s) {
      bf16x8 a0 = *(const bf16x8*)&As[((2 * w) * 128 + s * 64 + lane) * 8];
      bf16x8 a1 = *(const bf16x8*)&As[((2 * w + 1) * 128 + s * 64 + lane) * 8];
#pragma unroll
      for (int nt = 0; nt < 4; ++nt) {
        bf16x8 bfr = *(const bf16x8*)&Bs[(nt * 128 + s * 64 + lane) * 8];
        acc[0][nt] =
            __builtin_amdgcn_mfma_f32_16x16x32_bf16(a0, bfr, acc[0][nt], 0, 0, 0);
        acc[1][nt] =
            __builtin_amdgcn_mfma_f32_16x16x32_bf16(a1, bfr, acc[1][nt], 0, 0, 0);
      }
    }
  }
  const int g = lane >> 4, ml = lane & 15;
#pragma unroll
  for (int i = 0; i < 2; ++i)
#pragma unroll
    for (int r = 0; r < 4; ++r) {
      const int row = bm0 + (2 * w + i) * 16 + g * 4 + r;
      const int bb = row / NM, tt = row % NM;
      const int p1 = keep_idx[bb * NM + tt];
      const int p2 = dst2[bb * NM + tt];
#pragma unroll
      for (int nt = 0; nt < 4; ++nt) {
        const int col = bn0 + nt * 16 + ml;
        float v = acc[i][nt][r];
        out[((size_t)(bb * NN + p1)) * DM + col] = v;
        if (p2 >= 0) out[((size_t)(bb * NN + p2)) * DM + col] = v;
      }
    }
}

// ---------------------------------------------------------------------------
// 3-term hi/lo MFMA GEMM (fp32-accurate), async staging, 64x64 tiles.
// Split-K via blockIdx.z (separate outputs C0/C1).
// ---------------------------------------------------------------------------
__global__ __launch_bounds__(256) void gemm3t(
    const __bf16* __restrict__ Ah, const __bf16* __restrict__ Al,
    const __bf16* __restrict__ Bh, const __bf16* __restrict__ Bl,
    float* __restrict__ C0, float* __restrict__ C1, int M, int N, int K) {
  __shared__ __align__(16) __bf16 Ahs[4096], Als[4096], Bhs[4096], Bls[4096];
  const int z = blockIdx.z;
  float* C = z ? C1 : C0;
  const int kof = z * (K / 2);
  const int bm0 = blockIdx.x * 64;
  const int bn0 = blockIdx.y * 64;
  const int w = threadIdx.x >> 6;
  const int lane = threadIdx.x & 63;
  f32x4 acc[4];
#pragma unroll
  for (int nt = 0; nt < 4; ++nt) acc[nt] = (f32x4){0.f, 0.f, 0.f, 0.f};
  for (int kk = kof; kk < kof + K / 2; kk += 64) {
    __syncthreads();
#pragma unroll
    for (int it = 0; it < 2; ++it) {
      const int c = it * 256 + w * 64 + lane;
      const size_t ra = (size_t)(bm0 + ((c >> 7) << 4) + (c & 15)) * K;
      const size_t rb = (size_t)(bn0 + ((c >> 7) << 4) + (c & 15)) * K;
      const int col = kk + (((c >> 6) & 1) << 5) + (((c >> 4) & 3) << 3);
      const int lb = (it * 256 + w * 64) * 8;
      async16(Ah + ra + col, &Ahs[lb]);
      async16(Al + ra + col, &Als[lb]);
      async16(Bh + rb + col, &Bhs[lb]);
      async16(Bl + rb + col, &Bls[lb]);
    }
    __syncthreads();
#pragma unroll
    for (int s = 0; s < 2; ++s) {
      bf16x8 ah = *(const bf16x8*)&Ahs[((w * 2 + s) * 64 + lane) * 8];
      bf16x8 al = *(const bf16x8*)&Als[((w * 2 + s) * 64 + lane) * 8];
#pragma unroll
      for (int nt = 0; nt < 4; ++nt) {
        bf16x8 bh = *(const bf16x8*)&Bhs[((nt * 2 + s) * 64 + lane) * 8];
        bf16x8 bl = *(const bf16x8*)&Bls[((nt * 2 + s) * 64 + lane) * 8];
        acc[nt] = __builtin_amdgcn_mfma_f32_16x16x32_bf16(al, bh, acc[nt], 0, 0, 0);
        acc[nt] = __builtin_amdgcn_mfma_f32_16x16x32_bf16(ah, bl, acc[nt], 0, 0, 0);
        acc[nt] = __builtin_amdgcn_mfma_f32_16x16x32_bf16(ah, bh, acc[nt], 0, 0, 0);
      }
    }
  }
  const int g = lane >> 4, ml = lane & 15;
#pragma unroll
  for (int nt = 0; nt < 4; ++nt)
#pragma unroll
    for (int r = 0; r < 4; ++r)
      C[(size_t)(bm0 + w * 16 + g * 4 + r) * N + bn0 + nt * 16 + ml] =
          acc[nt][r];
}

// ---------------------------------------------------------------------------
// Scores 3-term GEMM with fused per-tile row-argmax epilogue (async staging).
// ---------------------------------------------------------------------------
__global__ __launch_bounds__(256) void gemm_scam(
    const __bf16* __restrict__ Ah, const __bf16* __restrict__ Al,
    const __bf16* __restrict__ Bh, const __bf16* __restrict__ Bl,
    float* __restrict__ sval, int* __restrict__ sidx) {
  __shared__ __align__(16) __bf16 Ahs[4096], Als[4096], Bhs[4096], Bls[4096];
  const size_t zo = (size_t)blockIdx.z * HALF * 256;
  const int bm0 = blockIdx.x * 64;
  const int bn0 = blockIdx.y * 64;
  const int w = threadIdx.x >> 6;
  const int lane = threadIdx.x & 63;
  f32x4 acc[4];
#pragma unroll
  for (int nt = 0; nt < 4; ++nt) acc[nt] = (f32x4){0.f, 0.f, 0.f, 0.f};
  for (int kk = 0; kk < 256; kk += 64) {
    __syncthreads();
#pragma unroll
    for (int it = 0; it < 2; ++it) {
      const int c = it * 256 + w * 64 + lane;
      const size_t ra = zo + (size_t)(bm0 + ((c >> 7) << 4) + (c & 15)) * 256;
      const size_t rb = zo + (size_t)(bn0 + ((c >> 7) << 4) + (c & 15)) * 256;
      const int col = kk + (((c >> 6) & 1) << 5) + (((c >> 4) & 3) << 3);
      const int lb = (it * 256 + w * 64) * 8;
      async16(Ah + ra + col, &Ahs[lb]);
      async16(Al + ra + col, &Als[lb]);
      async16(Bh + rb + col, &Bhs[lb]);
      async16(Bl + rb + col, &Bls[lb]);
    }
    __syncthreads();
#pragma unroll
    for (int s = 0; s < 2; ++s) {
      bf16x8 ah = *(const bf16x8*)&Ahs[((w * 2 + s) * 64 + lane) * 8];
      bf16x8 al = *(const bf16x8*)&Als[((w * 2 + s) * 64 + lane) * 8];
#pragma unroll
      for (int nt = 0; nt < 4; ++nt) {
        bf16x8 bh = *(const bf16x8*)&Bhs[((nt * 2 + s) * 64 + lane) * 8];
        bf16x8 bl = *(const bf16x8*)&Bls[((nt * 2 + s) * 64 + lane) * 8];
        acc[nt] = __builtin_amdgcn_mfma_f32_16x16x32_bf16(al, bh, acc[nt], 0, 0, 0);
        acc[nt] = __builtin_amdgcn_mfma_f32_16x16x32_bf16(ah, bl, acc[nt], 0, 0, 0);
        acc[nt] = __builtin_amdgcn_mfma_f32_16x16x32_bf16(ah, bh, acc[nt], 0, 0, 0);
      }
    }
  }
  const int g = lane >> 4, ml = lane & 15;
#pragma unroll
  for (int r = 0; r < 4; ++r) {
    float bv = acc[0][r];
    int bc = bn0 + ml;
#pragma unroll
    for (int nt = 1; nt < 4; ++nt) {
      float v = acc[nt][r];
      int c = bn0 + nt * 16 + ml;
      if (v > bv) { bv = v; bc = c; }
    }
#pragma unroll
    for (int off = 1; off < 16; off <<= 1) {
      float vo = __shfl_xor(bv, off, 64);
      int co = __shfl_xor(bc, off, 64);
      if (vo > bv || (vo == bv && co < bc)) { bv = vo; bc = co; }
    }
    if (ml == 0) {
      const int row = bm0 + w * 16 + g * 4 + r;
      const size_t o = ((size_t)blockIdx.z * HALF + row) * 16 + (bn0 >> 6);
      sval[o] = bv;
      sidx[o] = bc;
    }
  }
}

// ---------------------------------------------------------------------------
// Fused input prep: z<640 -> weight transposes; z>=640 -> x hi/lo split.
// ---------------------------------------------------------------------------
__global__ __launch_bounds__(256) void prep_in(
    const float* __restrict__ Wq, const float* __restrict__ Wk,
    const float* __restrict__ Wv, const float* __restrict__ Wo,
    const float* __restrict__ x, __bf16* __restrict__ Wqkvt,
    __bf16* __restrict__ Wktl, __bf16* __restrict__ Wot,
    __bf16* __restrict__ xh, __bf16* __restrict__ xl) {
  const int z = blockIdx.x;
  if (z >= 640) {
    const int i = (z - 640) * 256 + threadIdx.x;
    float4 v = ((const float4*)x)[i];
    float f[4] = {v.x, v.y, v.z, v.w};
    union { __bf16 h[4]; uint2 u; } H, L;
#pragma unroll
    for (int j = 0; j < 4; ++j) {
      __bf16 hh = (__bf16)f[j];
      H.h[j] = hh;
      L.h[j] = (__bf16)(f[j] - (float)hh);
    }
    ((uint2*)xh)[i] = H.u;
    ((uint2*)xl)[i] = L.u;
    return;
  }
  __shared__ float ld[64][65];
  const float* src;
  __bf16* dsth;
  __bf16* dstl = nullptr;
  int N, k0, n0, rowoff;
  if (z < 256) {
    src = Wq; N = 1024; k0 = (z >> 4) << 6; n0 = (z & 15) << 6;
    dsth = Wqkvt; rowoff = 0;
  } else if (z < 320) {
    int zz = z - 256;
    src = Wk; N = 256; k0 = (zz >> 2) << 6; n0 = (zz & 3) << 6;
    dsth = Wqkvt; rowoff = 1024; dstl = Wktl;
  } else if (z < 384) {
    int zz = z - 320;
    src = Wv; N = 256; k0 = (zz >> 2) << 6; n0 = (zz & 3) << 6;
    dsth = Wqkvt; rowoff = 1280;
  } else {
    int zz = z - 384;
    src = Wo; N = 1024; k0 = (zz >> 4) << 6; n0 = (zz & 15) << 6;
    dsth = Wot; rowoff = 0;
  }
  for (int i = threadIdx.x; i < 1024; i += 256) {
    int r = i >> 4, c4 = i & 15;
    float4 v = *(const float4*)(src + (size_t)(k0 + r) * N + n0 + c4 * 4);
    ld[r][c4 * 4 + 0] = v.x;
    ld[r][c4 * 4 + 1] = v.y;
    ld[r][c4 * 4 + 2] = v.z;
    ld[r][c4 * 4 + 3] = v.w;
  }
  __syncthreads();
  for (int i = threadIdx.x; i < 4096; i += 256) {
    int n = i >> 6, k = i & 63;
    float v = ld[k][n];
    __bf16 hh = (__bf16)v;
    dsth[(size_t)(rowoff + n0 + n) * 1024 + k0 + k] = hh;
    if (dstl)
      dstl[(size_t)(n0 + n) * 1024 + k0 + k] = (__bf16)(v - (float)hh);
  }
}

// ---------------------------------------------------------------------------
// Normalize metric rows (sum of split-K halves); write bf16 hi/lo.
// ---------------------------------------------------------------------------
__global__ __launch_bounds__(256) void normalize_split(
    const float* __restrict__ m0, const float* __restrict__ m1,
    __bf16* __restrict__ anh, __bf16* __restrict__ anl,
    __bf16* __restrict__ bnh, __bf16* __restrict__ bnl) {
  const int row = blockIdx.x;
  const int b = row >> 11;
  const int r = row & 2047;
  const int t = threadIdx.x;
  float v = m0[(size_t)row * 256 + t] + m1[(size_t)row * 256 + t];
  float ss = v * v;
#pragma unroll
  for (int o = 32; o > 0; o >>= 1) ss += __shfl_xor(ss, o, 64);
  __shared__ float wsum[4];
  if ((t & 63) == 0) wsum[t >> 6] = ss;
  __syncthreads();
  float tot = wsum[0] + wsum[1] + wsum[2] + wsum[3];
  float inv = 1.f / fmaxf(sqrtf(tot), 1e-12f);
  float nv = v * inv;
  __bf16 hh = (__bf16)nv;
  __bf16 ll = (__bf16)(nv - (float)hh);
  size_t o = ((size_t)b * HALF + (r >> 1)) * 256 + t;
  if (r & 1) {
    bnh[o] = hh;
    bnl[o] = ll;
  } else {
    anh[o] = hh;
    anl[o] = ll;
  }
}

// ---------------------------------------------------------------------------
// Fused: reduce 16 argmax partials per row (-> best_b) + stable descending
// bitonic argsort of the 1024 best scores per batch. 512 threads.
// ---------------------------------------------------------------------------
__global__ __launch_bounds__(512) void sort_desc(
    const float* __restrict__ sval, const int* __restrict__ sidx,
    int* __restrict__ best_b, int* __restrict__ order) {
  const int b = blockIdx.x;
  __shared__ float sv[1024];
  __shared__ int si[1024];
  for (int i = threadIdx.x; i < 1024; i += 512) {
    const size_t base = ((size_t)b * HALF + i) * 16;
    float bv = sval[base];
    int bc = sidx[base];
#pragma unroll
    for (int e = 1; e < 16; ++e) {
      float v = sval[base + e];
      int c = sidx[base + e];
      if (v > bv || (v == bv && c < bc)) { bv = v; bc = c; }
    }
    sv[i] = bv;
    si[i] = i;
    best_b[b * HALF + i] = bc;
  }
  __syncthreads();
  for (int k = 2; k <= 1024; k <<= 1) {
    for (int j = k >> 1; j > 0; j >>= 1) {
      for (int t = threadIdx.x; t < 1024; t += 512) {
        int ixj = t ^ j;
        if (ixj > t) {
          bool dir = ((t & k) == 0);
          float va = sv[t], vb = sv[ixj];
          int ia = si[t], ib = si[ixj];
          bool before = (vb > va) || (vb == va && ib < ia);
          if (before == dir) {
            sv[t] = vb; sv[ixj] = va;
            si[t] = ib; si[ixj] = ia;
          }
        }
      }
      __syncthreads();
    }
  }
  for (int i = threadIdx.x; i < 1024; i += 512) order[b * HALF + i] = si[i];
}

// ---------------------------------------------------------------------------
// Parallel greedy selection (exact serial-scan equivalent) + index maps.
// ---------------------------------------------------------------------------
__global__ __launch_bounds__(256) void select_and_index(
    const int* __restrict__ best_b, const int* __restrict__ order,
    int* __restrict__ keep_idx, int* __restrict__ partner,
    int* __restrict__ dst2) {
  const int b = blockIdx.x;
  __shared__ int rankA[HALF];
  __shared__ int minrank[HALF];
  __shared__ int taken[HALF];
  __shared__ int sel_a[RR], sel_b[RR];
  __shared__ int removed[NN];
  __shared__ int src_row[NN];
  __shared__ int tsum[256];
  const int t = threadIdx.x;

  for (int i = t; i < HALF; i += 256) { minrank[i] = 0x7fffffff; taken[i] = 0; }
  for (int i = t; i < NN; i += 256) {
    removed[i] = 0;
    partner[b * NN + i] = -1;
  }
  for (int i = t; i < NM; i += 256) dst2[b * NM + i] = -1;
  __syncthreads();
  int ord[4];
#pragma unroll
  for (int q = 0; q < 4; ++q) {
    int step = t * 4 + q;
    ord[q] = order[b * HALF + step];
    rankA[ord[q]] = step;
  }
  __syncthreads();
#pragma unroll
  for (int q = 0; q < 4; ++q) {
    int a = t * 4 + q;
    atomicMin(&minrank[best_b[b * HALF + a]], rankA[a]);
  }
  __syncthreads();
  for (int i = t; i < HALF; i += 256) {
    int mr = minrank[i];
    if (mr != 0x7fffffff) taken[mr] = 1;
  }
  __syncthreads();
  int c[4];
  int mysum = 0;
#pragma unroll
  for (int q = 0; q < 4; ++q) { c[q] = taken[t * 4 + q]; mysum += c[q]; }
  tsum[t] = mysum;
  __syncthreads();
  for (int off = 1; off < 256; off <<= 1) {
    int v = (t >= off) ? tsum[t - off] : 0;
    __syncthreads();
    tsum[t] += v;
    __syncthreads();
  }
  int run = tsum[t] - mysum;
#pragma unroll
  for (int q = 0; q < 4; ++q) {
    if (c[q] && run < RR) {
      int a = ord[q];
      sel_a[run] = 2 * a;
      sel_b[run] = 2 * best_b[b * HALF + a] + 1;
    }
    run += c[q];
  }
  __syncthreads();
  const int cnt = min(tsum[255], RR);
  if (t >= cnt) { sel_a[t] = sel_a[0]; sel_b[t] = sel_b[0]; }
  __syncthreads();
  {
    int ga = sel_a[t], gb = sel_b[t];
    removed[gb] = 1;
    partner[b * NN + ga] = gb;
  }
  __syncthreads();
  int myc = 0;
#pragma unroll
  for (int q = 0; q < 8; ++q) myc += !removed[8 * t + q];
  tsum[t] = myc;
  __syncthreads();
  for (int off = 1; off < 256; off <<= 1) {
    int v = (t >= off) ? tsum[t - off] : 0;
    __syncthreads();
    tsum[t] += v;
    __syncthreads();
  }
  int pos = tsum[t] - myc;
#pragma unroll
  for (int q = 0; q < 8; ++q) {
    int p = 8 * t + q;
    int sr = -1;
    if (!removed[p]) {
      if (pos < NM) {
        keep_idx[b * NM + pos] = p;
        sr = pos;
      }
      ++pos;
    }
    src_row[p] = sr;
  }
  __syncthreads();
  {
    int sr = src_row[sel_a[t]];
    dst2[b * NM + sr] = sel_b[t];
  }
}

// ---------------------------------------------------------------------------
// Merge -> bf16 x_mb
// ---------------------------------------------------------------------------
__global__ __launch_bounds__(256) void merge_kernel(
    const float* __restrict__ x, const int* __restrict__ keep_idx,
    const int* __restrict__ partner, __bf16* __restrict__ x_mb) {
  const int mrow = blockIdx.x;
  const int b = mrow / NM;
  const int t = mrow % NM;
  const int p = keep_idx[b * NM + t];
  const int pp = partner[b * NN + p];
  const float4* src =
      reinterpret_cast<const float4*>(x + ((size_t)b * NN + p) * DM);
  float4 val = src[threadIdx.x];
  if (pp >= 0) {
    const float4* s2 =
        reinterpret_cast<const float4*>(x + ((size_t)b * NN + pp) * DM);
    float4 v2 = s2[threadIdx.x];
    val.x = 0.5f * (val.x + v2.x);
    val.y = 0.5f * (val.y + v2.y);
    val.z = 0.5f * (val.z + v2.z);
    val.w = 0.5f * (val.w + v2.w);
  }
  union { __bf16 h[4]; uint2 u; } U;
  U.h[0] = (__bf16)val.x;
  U.h[1] = (__bf16)val.y;
  U.h[2] = (__bf16)val.z;
  U.h[3] = (__bf16)val.w;
  ((uint2*)(x_mb + (size_t)mrow * DM))[threadIdx.x] = U.u;
}

// ---------------------------------------------------------------------------
// Fused QKV post-processing: z < BB*NM -> RoPE q+k repack; else V transpose.
// ---------------------------------------------------------------------------
__global__ __launch_bounds__(256) void prep_qkv(
    const float* __restrict__ qkv, const float* __restrict__ fc,
    __bf16* __restrict__ qbh, __bf16* __restrict__ kbh,
    __bf16* __restrict__ vtb) {
  __shared__ float ld[64][65];
  const int z = blockIdx.x;
  if (z < BB * NM) {
    const int row = z;
    const int t = row % NM;
    const int b = row / NM;
    for (int idx = threadIdx.x; idx < 640; idx += 256) {
      int u = idx & 31;
      float c = fc[(t * 32 + u) * 2];
      float s = fc[(t * 32 + u) * 2 + 1];
      if (idx < 512) {
        int h = idx >> 5;
        const float* p = qkv + (size_t)row * 1536 + h * 64 + 2 * u;
        float x1 = p[0], x2 = p[1];
        __bf16* d = qbh + ((size_t)(b * NH + h) * NM + t) * 64 + 2 * u;
        d[0] = (__bf16)((x1 * c - x2 * s) * 0.125f);
        d[1] = (__bf16)((x1 * s + x2 * c) * 0.125f);
      } else {
        int h = (idx - 512) >> 5;
        const float* p = qkv + (size_t)row * 1536 + 1024 + h * 64 + 2 * u;
        float x1 = p[0], x2 = p[1];
        __bf16* d = kbh + ((size_t)(b * NKV + h) * NM + t) * 64 + 2 * u;
        d[0] = (__bf16)(x1 * c - x2 * s);
        d[1] = (__bf16)(x1 * s + x2 * c);
      }
    }
    return;
  }
  int bid = z - BB * NM;
  const int kt = bid % (NM / 64); bid /= (NM / 64);
  const int kvh = bid % NKV;
  const int b = bid / NKV;
  const int j0 = kt * 64;
  for (int t2 = threadIdx.x; t2 < 1024; t2 += 256) {
    int key = t2 >> 4, c4 = t2 & 15;
    float4 v4 = *reinterpret_cast<const float4*>(
        qkv + (size_t)(b * NM + j0 + key) * 1536 + 1280 + kvh * 64 + c4 * 4);
    ld[key][c4 * 4 + 0] = v4.x;
    ld[key][c4 * 4 + 1] = v4.y;
    ld[key][c4 * 4 + 2] = v4.z;
    ld[key][c4 * 4 + 3] = v4.w;
  }
  __syncthreads();
  const int dim = threadIdx.x >> 2, kc = threadIdx.x & 3;
  __bf16* out = vtb + ((size_t)(b * NKV + kvh) * 64 + dim) * NM + j0 + kc * 16;
#pragma unroll
  for (int kk = 0; kk < 16; ++kk) out[kk] = (__bf16)ld[kc * 16 + kk][dim];
}

// ---------------------------------------------------------------------------
// Flash attention, bf16 MFMA, S^T orientation, fixed-shift softmax,
// split-K over NSPL=4, 8-wave blocks (R10 config), single-buffer async K/V.
// P routed through padded PER-WAVE LDS (4 ds_write_b64 + 2 ds_read_b128,
// conflict-free, no barrier) instead of 16 ds_bpermute shuffles.
// ---------------------------------------------------------------------------
#define LDP 72  // padded P row stride (bf16): 2-way bank alias only (free)

__global__ __launch_bounds__(512) void attn_mfma(
    const __bf16* __restrict__ qbh, const __bf16* __restrict__ kbh,
    const __bf16* __restrict__ vtb, float* __restrict__ pl,
    __bf16* __restrict__ pacc) {
  __shared__ __align__(16) __bf16 Ks[4096];
  __shared__ __align__(16) __bf16 Vs[4096];
  __shared__ __align__(16) __bf16 Pt[8 * 16 * LDP];
  int bid = blockIdx.x;
  const int qt2 = bid % (NM / 32); bid /= (NM / 32);
  const int split = bid % NSPL; bid /= NSPL;
  const int kvh = bid % NKV;
  const int b = bid / NKV;
  const int w = threadIdx.x >> 6;
  const int lane = threadIdx.x & 63;
  const int h = kvh * 4 + (w & 3);
  const int qt = qt2 * 32 + (w >> 2) * 16;
  const int g = lane >> 4;
  const int ml = lane & 15;
  __bf16* Pw = Pt + w * 16 * LDP;

  const __bf16* qrow = qbh + ((size_t)(b * NH + h) * NM + qt + ml) * 64;
  bf16x8 qa0 = *reinterpret_cast<const bf16x8*>(qrow + g * 8);
  bf16x8 qa1 = *reinterpret_cast<const bf16x8*>(qrow + 32 + g * 8);

  f32x4 acc[4];
#pragma unroll
  for (int mt = 0; mt < 4; ++mt) acc[mt] = (f32x4){0.f, 0.f, 0.f, 0.f};
  float lsum = 0.f;

  const __bf16* kp = kbh + (size_t)(b * NKV + kvh) * NM * 64;
  const __bf16* vp = vtb + (size_t)(b * NKV + kvh) * 64 * NM;

  const int jt0 = split * (NT / NSPL);
  for (int jt = jt0; jt < jt0 + NT / NSPL; ++jt) {
    __syncthreads();
    {
      const int c = threadIdx.x;  // 512 chunks each for Ks and Vs
      const int lb = w * 512;
      async16(kp + (size_t)(jt * 64 + ((c >> 7) << 4) + (c & 15)) * 64 +
                  (((c >> 6) & 1) << 5) + (((c >> 4) & 3) << 3),
              &Ks[lb]);
      async16(vp + (size_t)(((c >> 7) << 4) + (c & 15)) * NM + jt * 64 +
                  (((c >> 6) & 1) << 5) + (((c >> 4) & 3) << 3),
              &Vs[lb]);
    }
    __syncthreads();
    f32x4 S[4];
#pragma unroll
    for (int nt = 0; nt < 4; ++nt) {
      bf16x8 k0 = *(const bf16x8*)&Ks[(nt * 128 + lane) * 8];
      bf16x8 k1 = *(const bf16x8*)&Ks[(nt * 128 + 64 + lane) * 8];
      f32x4 s4 = (f32x4){0.f, 0.f, 0.f, 0.f};
      s4 = __builtin_amdgcn_mfma_f32_16x16x32_bf16(k0, qa0, s4, 0, 0, 0);
      s4 = __builtin_amdgcn_mfma_f32_16x16x32_bf16(k1, qa1, s4, 0, 0, 0);
      S[nt] = s4;
    }
    // S[nt][r] = score for query ml, key nt*16 + g*4 + r (fixed shift exp)
#pragma unroll
    for (int nt = 0; nt < 4; ++nt) {
      float p0 = __expf(S[nt][0]);
      float p1 = __expf(S[nt][1]);
      float p2 = __expf(S[nt][2]);
      float p3 = __expf(S[nt][3]);
      lsum += (p0 + p1) + (p2 + p3);
      uint2 u;
      u.x = pk2(p0, p1);
      u.y = pk2(p2, p3);
      // P[q=ml][key = nt*16 + g*4 .. +3] -> per-wave LDS (b64, 2-way free)
      *reinterpret_cast<uint2*>(&Pw[ml * LDP + nt * 16 + g * 4]) = u;
    }
    // read back as B-operand fragment: B[k=key=g*8+j][n=q=ml]
    bf16x8 P0 = *(const bf16x8*)&Pw[ml * LDP + g * 8];
    bf16x8 P1 = *(const bf16x8*)&Pw[ml * LDP + 32 + g * 8];
#pragma unroll
    for (int mt = 0; mt < 4; ++mt) {
      bf16x8 v0 = *(const bf16x8*)&Vs[(mt * 128 + lane) * 8];
      bf16x8 v1 = *(const bf16x8*)&Vs[(mt * 128 + 64 + lane) * 8];
      acc[mt] = __builtin_amdgcn_mfma_f32_16x16x32_bf16(v0, P0, acc[mt], 0, 0, 0);
      acc[mt] = __builtin_amdgcn_mfma_f32_16x16x32_bf16(v1, P1, acc[mt], 0, 0, 0);
    }
  }
  lsum += __shfl_xor(lsum, 16, 64);
  lsum += __shfl_xor(lsum, 32, 64);
  const size_t row = (size_t)(b * NH + h) * NM + qt + ml;
  if (g == 0) pl[row * NSPL + split] = lsum;
  __bf16* pa = pacc + (row * NSPL + split) * 64;
#pragma unroll
  for (int mt = 0; mt < 4; ++mt) {
    uint2 u;
    u.x = pk2(acc[mt][0], acc[mt][1]);
    u.y = pk2(acc[mt][2], acc[mt][3]);
    *reinterpret_cast<uint2*>(pa + mt * 16 + g * 4) = u;
  }
}

// ---------------------------------------------------------------------------
// Split-K combine (fixed shift: plain sums) -> bf16 attn_ob
// ---------------------------------------------------------------------------
__global__ __launch_bounds__(256) void attn_combine(
    const float* __restrict__ pl, const __bf16* __restrict__ pacc,
    __bf16* __restrict__ attn_ob) {
  const size_t rid = (size_t)blockIdx.x * 4 + (threadIdx.x >> 6);
  const int d = threadIdx.x & 63;
  float num = 0.f, den = 0.f;
#pragma unroll
  for (int s = 0; s < NSPL; ++s) {
    num += (float)pacc[(rid * NSPL + s) * 64 + d];
    den += pl[rid * NSPL + s];
  }
  float o = num / den;
  const int q = (int)(rid % NM);
  const int h = (int)((rid / NM) % NH);
  const int b = (int)(rid / ((size_t)NM * NH));
  attn_ob[((size_t)(b * NM + q)) * DM + h * 64 + d] = (__bf16)o;
}

// ---------------------------------------------------------------------------
extern "C" void kernel_launch(void* const* d_in, const int* in_sizes, int n_in,
                              void* d_out, int out_size, void* d_ws,
                              size_t ws_size, hipStream_t stream) {
  const float* x = (const float*)d_in[0];
  const float* fc = (const float*)d_in[1];
  const float* Wq = (const float*)d_in[2];
  const float* Wk = (const float*)d_in[3];
  const float* Wv = (const float*)d_in[4];
  const float* Wo = (const float*)d_in[5];
  float* out = (float*)d_out;

  char* ws = (char*)d_ws;
  size_t off = 0;
  auto alloc = [&](size_t bytes) {
    void* p = ws + off;
    off += (bytes + 255) & ~(size_t)255;
    return p;
  };
  float* metric0 = (float*)alloc((size_t)BB * NN * 256 * 4);
  float* metric1 = (float*)alloc((size_t)BB * NN * 256 * 4);
  int* best_b = (int*)alloc((size_t)BB * HALF * 4);
  int* order = (int*)alloc((size_t)BB * HALF * 4);
  int* keep_idx = (int*)alloc((size_t)BB * NM * 4);
  int* partner = (int*)alloc((size_t)BB * NN * 4);
  int* dst2 = (int*)alloc((size_t)BB * NM * 4);
  float* sval = (float*)alloc((size_t)BB * HALF * 16 * 4);
  int* sidx = (int*)alloc((size_t)BB * HALF * 16 * 4);
  char* bigreg = (char*)alloc((size_t)30 * 1024 * 1024);
  __bf16* xh = (__bf16*)bigreg;
  __bf16* xl = (__bf16*)(bigreg + (size_t)8704 * 1024);
  __bf16* anh = (__bf16*)bigreg;
  __bf16* anl = (__bf16*)(bigreg + (size_t)1100 * 1024);
  __bf16* bnh = (__bf16*)(bigreg + (size_t)2200 * 1024);
  __bf16* bnl = (__bf16*)(bigreg + (size_t)3300 * 1024);
  float* qkv = (float*)bigreg;
  __bf16* pacc = (__bf16*)bigreg;
  __bf16* x_mb = (__bf16*)alloc((size_t)BB * NM * DM * 2);
  __bf16* qbh = (__bf16*)alloc((size_t)BB * NH * NM * 64 * 2);
  __bf16* kbh = (__bf16*)alloc((size_t)BB * NKV * NM * 64 * 2);
  __bf16* vtb = (__bf16*)alloc((size_t)BB * NKV * 64 * NM * 2);
  __bf16* attn_ob = (__bf16*)alloc((size_t)BB * NM * DM * 2);
  float* pl = (float*)alloc((size_t)BB * NH * NM * NSPL * 4);
  __bf16* Wqkvt = (__bf16*)alloc((size_t)1536 * DM * 2);
  __bf16* Wktl = (__bf16*)alloc((size_t)256 * DM * 2);
  __bf16* Wot = (__bf16*)alloc((size_t)DM * DM * 2);
  const __bf16* Wkth = Wqkvt + (size_t)1024 * 1024;

  // ---- fused prep: weight transposes + x hi/lo split
  prep_in<<<640 + (BB * NN * DM / 4) / 256, 256, 0, stream>>>(
      Wq, Wk, Wv, Wo, x, Wqkvt, Wktl, Wot, xh, xl);
  // ---- metric = x @ Wk (3-term hi/lo MFMA, split-K x2)
  gemm3t<<<dim3(64, 4, 2), 256, 0, stream>>>(xh, xl, Wkth, Wktl, metric0,
                                             metric1, BB * NN, 256, DM);
  normalize_split<<<BB * NN, 256, 0, stream>>>(metric0, metric1, anh, anl, bnh,
                                               bnl);
  gemm_scam<<<dim3(16, 16, 2), 256, 0, stream>>>(anh, anl, bnh, bnl, sval,
                                                 sidx);
  // ---- fused argmax-reduce + sort
  sort_desc<<<BB, 512, 0, stream>>>(sval, sidx, best_b, order);
  select_and_index<<<BB, 256, 0, stream>>>(best_b, order, keep_idx, partner,
                                           dst2);
  merge_kernel<<<BB * NM, 256, 0, stream>>>(x, keep_idx, partner, x_mb);
  // ---- fused QKV projection
  gemm_bf16<<<dim3(28, 24), 256, 0, stream>>>(x_mb, Wqkvt, qkv, BB * NM, 1536,
                                              DM);
  // ---- fused RoPE + V repack
  prep_qkv<<<BB * NM + BB * NKV * (NM / 64), 256, 0, stream>>>(qkv, fc, qbh,
                                                               kbh, vtb);
  // ---- attention (512-thr blocks, split-K x4, LDS-P) + combine
  attn_mfma<<<BB * NKV * NSPL * (NM / 32), 512, 0, stream>>>(qbh, kbh, vtb, pl,
                                                             pacc);
  attn_combine<<<(BB * NH * NM) / 4, 256, 0, stream>>>(pl, pacc, attn_ob);
  // ---- output projection with fused unmerge scatter
  gemm_wo<<<dim3(28, 16), 256, 0, stream>>>(attn_ob, Wot, keep_idx, dst2, out,
                                            BB * NM, DM, DM);
}

// Round 14
// 285.533 us; speedup vs baseline: 1.0539x; 1.0035x over previous
//
#include <hip/hip_runtime.h>
#include <hip/hip_bf16.h>
#include <math.h>

// Problem constants
#define BB 2
#define NN 2048
#define DM 1024
#define NH 16
#define NKV 4
#define HD 64
#define RR 256
#define HALF 1024
#define NM 1792   // NN - RR
#define NT 28     // key tiles of 64
#define NSPL 4    // attention split-K

typedef __bf16 bf16x8 __attribute__((ext_vector_type(8)));
typedef float f32x4 __attribute__((ext_vector_type(4)));

__device__ inline unsigned pk2(float a, float b) {
  union { __bf16 h; unsigned short u; } ua, ub;
  ua.h = (__bf16)a;
  ub.h = (__bf16)b;
  return (unsigned)ua.u | ((unsigned)ub.u << 16);
}

// Async global->LDS, 16B per lane. LDS dest = wave-uniform base + lane*16.
__device__ __forceinline__ void async16(const void* g, void* l) {
  __builtin_amdgcn_global_load_lds(
      (const __attribute__((address_space(1))) void*)g,
      (__attribute__((address_space(3))) void*)l, 16, 0, 0);
}

// ---------------------------------------------------------------------------
// bf16 MFMA GEMM: C[M x N] = A[M x K] @ Bt[N x K]^T.  Block tile 128x64,
// wave tile 32x64. Fragment-linear LDS; staging via global_load_lds (16B).
// ---------------------------------------------------------------------------
__global__ __launch_bounds__(256) void gemm_bf16(
    const __bf16* __restrict__ A, const __bf16* __restrict__ Bt,
    float* __restrict__ C, int M, int N, int K) {
  __shared__ __align__(16) __bf16 As[8192];  // 128 x 64
  __shared__ __align__(16) __bf16 Bs[4096];  // 64 x 64
  const int bm0 = blockIdx.x * 128;
  const int bn0 = blockIdx.y * 64;
  const int w = threadIdx.x >> 6;
  const int lane = threadIdx.x & 63;
  f32x4 acc[2][4];
#pragma unroll
  for (int i = 0; i < 2; ++i)
#pragma unroll
    for (int nt = 0; nt < 4; ++nt) acc[i][nt] = (f32x4){0.f, 0.f, 0.f, 0.f};
  for (int kk = 0; kk < K; kk += 64) {
    __syncthreads();
#pragma unroll
    for (int it = 0; it < 4; ++it) {
      const int c = it * 256 + w * 64 + lane;
      async16(A + (size_t)(bm0 + ((c >> 7) << 4) + (c & 15)) * K + kk +
                  (((c >> 6) & 1) << 5) + (((c >> 4) & 3) << 3),
              &As[(it * 256 + w * 64) * 8]);
    }
#pragma unroll
    for (int it = 0; it < 2; ++it) {
      const int c = it * 256 + w * 64 + lane;
      async16(Bt + (size_t)(bn0 + ((c >> 7) << 4) + (c & 15)) * K + kk +
                  (((c >> 6) & 1) << 5) + (((c >> 4) & 3) << 3),
              &Bs[(it * 256 + w * 64) * 8]);
    }
    __syncthreads();
#pragma unroll
    for (int s = 0; s < 2; ++s) {
      bf16x8 a0 = *(const bf16x8*)&As[((2 * w) * 128 + s * 64 + lane) * 8];
      bf16x8 a1 = *(const bf16x8*)&As[((2 * w + 1) * 128 + s * 64 + lane) * 8];
#pragma unroll
      for (int nt = 0; nt < 4; ++nt) {
        bf16x8 bfr = *(const bf16x8*)&Bs[(nt * 128 + s * 64 + lane) * 8];
        acc[0][nt] =
            __builtin_amdgcn_mfma_f32_16x16x32_bf16(a0, bfr, acc[0][nt], 0, 0, 0);
        acc[1][nt] =
            __builtin_amdgcn_mfma_f32_16x16x32_bf16(a1, bfr, acc[1][nt], 0, 0, 0);
      }
    }
  }
  const int g = lane >> 4, ml = lane & 15;
#pragma unroll
  for (int i = 0; i < 2; ++i)
#pragma unroll
    for (int nt = 0; nt < 4; ++nt)
#pragma unroll
      for (int r = 0; r < 4; ++r)
        C[(size_t)(bm0 + (2 * w + i) * 16 + g * 4 + r) * N + bn0 + nt * 16 +
          ml] = acc[i][nt][r];
}

// ---------------------------------------------------------------------------
// Wo GEMM (128x64 tiles, async staging) with fused unmerge-scatter epilogue.
// ---------------------------------------------------------------------------
__global__ __launch_bounds__(256) void gemm_wo(
    const __bf16* __restrict__ A, const __bf16* __restrict__ Bt,
    const int* __restrict__ keep_idx, const int* __restrict__ dst2,
    float* __restrict__ out, int M, int N, int K) {
  __shared__ __align__(16) __bf16 As[8192];
  __shared__ __align__(16) __bf16 Bs[4096];
  const int bm0 = blockIdx.x * 128;
  const int bn0 = blockIdx.y * 64;
  const int w = threadIdx.x >> 6;
  const int lane = threadIdx.x & 63;
  f32x4 acc[2][4];
#pragma unroll
  for (int i = 0; i < 2; ++i)
#pragma unroll
    for (int nt = 0; nt < 4; ++nt) acc[i][nt] = (f32x4){0.f, 0.f, 0.f, 0.f};
  for (int kk = 0; kk < K; kk += 64) {
    __syncthreads();
#pragma unroll
    for (int it = 0; it < 4; ++it) {
      const int c = it * 256 + w * 64 + lane;
      async16(A + (size_t)(bm0 + ((c >> 7) << 4) + (c & 15)) * K + kk +
                  (((c >> 6) & 1) << 5) + (((c >> 4) & 3) << 3),
              &As[(it * 256 + w * 64) * 8]);
    }
#pragma unroll
    for (int it = 0; it < 2; ++it) {
      const int c = it * 256 + w * 64 + lane;
      async16(Bt + (size_t)(bn0 + ((c >> 7) << 4) + (c & 15)) * K + kk +
                  (((c >> 6) & 1) << 5) + (((c >> 4) & 3) << 3),
              &Bs[(it * 256 + w * 64) * 8]);
    }
    __syncthreads();
#pragma unroll
    for (int s = 0; s < 2; ++s) {
      bf16x8 a0 = *(const bf16x8*)&As[((2 * w) * 128 + s * 64 + lane) * 8];
      bf16x8 a1 = *(const bf16x8*)&As[((2 * w + 1) * 128 + s * 64 + lane) * 8];
#pragma unroll
      for (int nt = 0; nt < 4; ++nt) {
        bf16x8 bfr = *(const bf16x8*)&Bs[(nt * 128 + s * 64 + lane) * 8];
        acc[0][nt] =
            __builtin_amdgcn_mfma_f32_16x16x32_bf16(a0, bfr, acc[0][nt], 0, 0, 0);
        acc[1][nt] =
            __builtin_amdgcn_mfma_f32_16x16x32_bf16(a1, bfr, acc[1][nt], 0, 0, 0);
      }
    }
  }
  const int g = lane >> 4, ml = lane & 15;
#pragma unroll
  for (int i = 0; i < 2; ++i)
#pragma unroll
    for (int r = 0; r < 4; ++r) {
      const int row = bm0 + (2 * w + i) * 16 + g * 4 + r;
      const int bb = row / NM, tt = row % NM;
      const int p1 = keep_idx[bb * NM + tt];
      const int p2 = dst2[bb * NM + tt];
#pragma unroll
      for (int nt = 0; nt < 4; ++nt) {
        const int col = bn0 + nt * 16 + ml;
        float v = acc[i][nt][r];
        out[((size_t)(bb * NN + p1)) * DM + col] = v;
        if (p2 >= 0) out[((size_t)(bb * NN + p2)) * DM + col] = v;
      }
    }
}

// ---------------------------------------------------------------------------
// 3-term hi/lo MFMA GEMM (fp32-accurate), async staging, 128x64 block tile
// (2 rows/wave: 48 MFMAs per 24 LDS reads per k-iter). Split-K x4 via
// blockIdx.z -> separate outputs C0..C3 (summed in normalize).
// ---------------------------------------------------------------------------
__global__ __launch_bounds__(256) void gemm3t(
    const __bf16* __restrict__ Ah, const __bf16* __restrict__ Al,
    const __bf16* __restrict__ Bh, const __bf16* __restrict__ Bl,
    float* __restrict__ C0, float* __restrict__ C1, float* __restrict__ C2,
    float* __restrict__ C3, int M, int N, int K) {
  __shared__ __align__(16) __bf16 Ahs[8192], Als[8192];
  __shared__ __align__(16) __bf16 Bhs[4096], Bls[4096];
  const int z = blockIdx.z;
  float* C = (z == 0) ? C0 : (z == 1) ? C1 : (z == 2) ? C2 : C3;
  const int kof = z * (K / 4);
  const int bm0 = blockIdx.x * 128;
  const int bn0 = blockIdx.y * 64;
  const int w = threadIdx.x >> 6;
  const int lane = threadIdx.x & 63;
  f32x4 acc[2][4];
#pragma unroll
  for (int i = 0; i < 2; ++i)
#pragma unroll
    for (int nt = 0; nt < 4; ++nt) acc[i][nt] = (f32x4){0.f, 0.f, 0.f, 0.f};
  for (int kk = kof; kk < kof + K / 4; kk += 64) {
    __syncthreads();
#pragma unroll
    for (int it = 0; it < 4; ++it) {
      const int c = it * 256 + w * 64 + lane;
      const size_t ra = (size_t)(bm0 + ((c >> 7) << 4) + (c & 15)) * K;
      const int col = kk + (((c >> 6) & 1) << 5) + (((c >> 4) & 3) << 3);
      const int lb = (it * 256 + w * 64) * 8;
      async16(Ah + ra + col, &Ahs[lb]);
      async16(Al + ra + col, &Als[lb]);
    }
#pragma unroll
    for (int it = 0; it < 2; ++it) {
      const int c = it * 256 + w * 64 + lane;
      const size_t rb = (size_t)(bn0 + ((c >> 7) << 4) + (c & 15)) * K;
      const int col = kk + (((c >> 6) & 1) << 5) + (((c >> 4) & 3) << 3);
      const int lb = (it * 256 + w * 64) * 8;
      async16(Bh + rb + col, &Bhs[lb]);
      async16(Bl + rb + col, &Bls[lb]);
    }
    __syncthreads();
#pragma unroll
    for (int s = 0; s < 2; ++s) {
      bf16x8 ah0 = *(const bf16x8*)&Ahs[((2 * w) * 128 + s * 64 + lane) * 8];
      bf16x8 ah1 = *(const bf16x8*)&Ahs[((2 * w + 1) * 128 + s * 64 + lane) * 8];
      bf16x8 al0 = *(const bf16x8*)&Als[((2 * w) * 128 + s * 64 + lane) * 8];
      bf16x8 al1 = *(const bf16x8*)&Als[((2 * w + 1) * 128 + s * 64 + lane) * 8];
#pragma unroll
      for (int nt = 0; nt < 4; ++nt) {
        bf16x8 bh = *(const bf16x8*)&Bhs[(nt * 128 + s * 64 + lane) * 8];
        bf16x8 bl = *(const bf16x8*)&Bls[(nt * 128 + s * 64 + lane) * 8];
        acc[0][nt] = __builtin_amdgcn_mfma_f32_16x16x32_bf16(al0, bh, acc[0][nt], 0, 0, 0);
        acc[0][nt] = __builtin_amdgcn_mfma_f32_16x16x32_bf16(ah0, bl, acc[0][nt], 0, 0, 0);
        acc[0][nt] = __builtin_amdgcn_mfma_f32_16x16x32_bf16(ah0, bh, acc[0][nt], 0, 0, 0);
        acc[1][nt] = __builtin_amdgcn_mfma_f32_16x16x32_bf16(al1, bh, acc[1][nt], 0, 0, 0);
        acc[1][nt] = __builtin_amdgcn_mfma_f32_16x16x32_bf16(ah1, bl, acc[1][nt], 0, 0, 0);
        acc[1][nt] = __builtin_amdgcn_mfma_f32_16x16x32_bf16(ah1, bh, acc[1][nt], 0, 0, 0);
      }
    }
  }
  const int g = lane >> 4, ml = lane & 15;
#pragma unroll
  for (int i = 0; i < 2; ++i)
#pragma unroll
    for (int nt = 0; nt < 4; ++nt)
#pragma unroll
      for (int r = 0; r < 4; ++r)
        C[(size_t)(bm0 + (2 * w + i) * 16 + g * 4 + r) * N + bn0 + nt * 16 +
          ml] = acc[i][nt][r];
}

// ---------------------------------------------------------------------------
// Scores 3-term GEMM with fused per-tile row-argmax epilogue (async staging).
// ---------------------------------------------------------------------------
__global__ __launch_bounds__(256) void gemm_scam(
    const __bf16* __restrict__ Ah, const __bf16* __restrict__ Al,
    const __bf16* __restrict__ Bh, const __bf16* __restrict__ Bl,
    float* __restrict__ sval, int* __restrict__ sidx) {
  __shared__ __align__(16) __bf16 Ahs[4096], Als[4096], Bhs[4096], Bls[4096];
  const size_t zo = (size_t)blockIdx.z * HALF * 256;
  const int bm0 = blockIdx.x * 64;
  const int bn0 = blockIdx.y * 64;
  const int w = threadIdx.x >> 6;
  const int lane = threadIdx.x & 63;
  f32x4 acc[4];
#pragma unroll
  for (int nt = 0; nt < 4; ++nt) acc[nt] = (f32x4){0.f, 0.f, 0.f, 0.f};
  for (int kk = 0; kk < 256; kk += 64) {
    __syncthreads();
#pragma unroll
    for (int it = 0; it < 2; ++it) {
      const int c = it * 256 + w * 64 + lane;
      const size_t ra = zo + (size_t)(bm0 + ((c >> 7) << 4) + (c & 15)) * 256;
      const size_t rb = zo + (size_t)(bn0 + ((c >> 7) << 4) + (c & 15)) * 256;
      const int col = kk + (((c >> 6) & 1) << 5) + (((c >> 4) & 3) << 3);
      const int lb = (it * 256 + w * 64) * 8;
      async16(Ah + ra + col, &Ahs[lb]);
      async16(Al + ra + col, &Als[lb]);
      async16(Bh + rb + col, &Bhs[lb]);
      async16(Bl + rb + col, &Bls[lb]);
    }
    __syncthreads();
#pragma unroll
    for (int s = 0; s < 2; ++s) {
      bf16x8 ah = *(const bf16x8*)&Ahs[((w * 2 + s) * 64 + lane) * 8];
      bf16x8 al = *(const bf16x8*)&Als[((w * 2 + s) * 64 + lane) * 8];
#pragma unroll
      for (int nt = 0; nt < 4; ++nt) {
        bf16x8 bh = *(const bf16x8*)&Bhs[((nt * 2 + s) * 64 + lane) * 8];
        bf16x8 bl = *(const bf16x8*)&Bls[((nt * 2 + s) * 64 + lane) * 8];
        acc[nt] = __builtin_amdgcn_mfma_f32_16x16x32_bf16(al, bh, acc[nt], 0, 0, 0);
        acc[nt] = __builtin_amdgcn_mfma_f32_16x16x32_bf16(ah, bl, acc[nt], 0, 0, 0);
        acc[nt] = __builtin_amdgcn_mfma_f32_16x16x32_bf16(ah, bh, acc[nt], 0, 0, 0);
      }
    }
  }
  const int g = lane >> 4, ml = lane & 15;
#pragma unroll
  for (int r = 0; r < 4; ++r) {
    float bv = acc[0][r];
    int bc = bn0 + ml;
#pragma unroll
    for (int nt = 1; nt < 4; ++nt) {
      float v = acc[nt][r];
      int c = bn0 + nt * 16 + ml;
      if (v > bv) { bv = v; bc = c; }
    }
#pragma unroll
    for (int off = 1; off < 16; off <<= 1) {
      float vo = __shfl_xor(bv, off, 64);
      int co = __shfl_xor(bc, off, 64);
      if (vo > bv || (vo == bv && co < bc)) { bv = vo; bc = co; }
    }
    if (ml == 0) {
      const int row = bm0 + w * 16 + g * 4 + r;
      const size_t o = ((size_t)blockIdx.z * HALF + row) * 16 + (bn0 >> 6);
      sval[o] = bv;
      sidx[o] = bc;
    }
  }
}

// ---------------------------------------------------------------------------
// Fused input prep: z<640 -> weight transposes; z>=640 -> x hi/lo split.
// ---------------------------------------------------------------------------
__global__ __launch_bounds__(256) void prep_in(
    const float* __restrict__ Wq, const float* __restrict__ Wk,
    const float* __restrict__ Wv, const float* __restrict__ Wo,
    const float* __restrict__ x, __bf16* __restrict__ Wqkvt,
    __bf16* __restrict__ Wktl, __bf16* __restrict__ Wot,
    __bf16* __restrict__ xh, __bf16* __restrict__ xl) {
  const int z = blockIdx.x;
  if (z >= 640) {
    const int i = (z - 640) * 256 + threadIdx.x;
    float4 v = ((const float4*)x)[i];
    float f[4] = {v.x, v.y, v.z, v.w};
    union { __bf16 h[4]; uint2 u; } H, L;
#pragma unroll
    for (int j = 0; j < 4; ++j) {
      __bf16 hh = (__bf16)f[j];
      H.h[j] = hh;
      L.h[j] = (__bf16)(f[j] - (float)hh);
    }
    ((uint2*)xh)[i] = H.u;
    ((uint2*)xl)[i] = L.u;
    return;
  }
  __shared__ float ld[64][65];
  const float* src;
  __bf16* dsth;
  __bf16* dstl = nullptr;
  int N, k0, n0, rowoff;
  if (z < 256) {
    src = Wq; N = 1024; k0 = (z >> 4) << 6; n0 = (z & 15) << 6;
    dsth = Wqkvt; rowoff = 0;
  } else if (z < 320) {
    int zz = z - 256;
    src = Wk; N = 256; k0 = (zz >> 2) << 6; n0 = (zz & 3) << 6;
    dsth = Wqkvt; rowoff = 1024; dstl = Wktl;
  } else if (z < 384) {
    int zz = z - 320;
    src = Wv; N = 256; k0 = (zz >> 2) << 6; n0 = (zz & 3) << 6;
    dsth = Wqkvt; rowoff = 1280;
  } else {
    int zz = z - 384;
    src = Wo; N = 1024; k0 = (zz >> 4) << 6; n0 = (zz & 15) << 6;
    dsth = Wot; rowoff = 0;
  }
  for (int i = threadIdx.x; i < 1024; i += 256) {
    int r = i >> 4, c4 = i & 15;
    float4 v = *(const float4*)(src + (size_t)(k0 + r) * N + n0 + c4 * 4);
    ld[r][c4 * 4 + 0] = v.x;
    ld[r][c4 * 4 + 1] = v.y;
    ld[r][c4 * 4 + 2] = v.z;
    ld[r][c4 * 4 + 3] = v.w;
  }
  __syncthreads();
  for (int i = threadIdx.x; i < 4096; i += 256) {
    int n = i >> 6, k = i & 63;
    float v = ld[k][n];
    __bf16 hh = (__bf16)v;
    dsth[(size_t)(rowoff + n0 + n) * 1024 + k0 + k] = hh;
    if (dstl)
      dstl[(size_t)(n0 + n) * 1024 + k0 + k] = (__bf16)(v - (float)hh);
  }
}

// ---------------------------------------------------------------------------
// Normalize metric rows (sum of 4 split-K partials); write bf16 hi/lo.
// ---------------------------------------------------------------------------
__global__ __launch_bounds__(256) void normalize_split(
    const float* __restrict__ m0, const float* __restrict__ m1,
    const float* __restrict__ m2, const float* __restrict__ m3,
    __bf16* __restrict__ anh, __bf16* __restrict__ anl,
    __bf16* __restrict__ bnh, __bf16* __restrict__ bnl) {
  const int row = blockIdx.x;
  const int b = row >> 11;
  const int r = row & 2047;
  const int t = threadIdx.x;
  const size_t ix = (size_t)row * 256 + t;
  float v = (m0[ix] + m1[ix]) + (m2[ix] + m3[ix]);
  float ss = v * v;
#pragma unroll
  for (int o = 32; o > 0; o >>= 1) ss += __shfl_xor(ss, o, 64);
  __shared__ float wsum[4];
  if ((t & 63) == 0) wsum[t >> 6] = ss;
  __syncthreads();
  float tot = wsum[0] + wsum[1] + wsum[2] + wsum[3];
  float inv = 1.f / fmaxf(sqrtf(tot), 1e-12f);
  float nv = v * inv;
  __bf16 hh = (__bf16)nv;
  __bf16 ll = (__bf16)(nv - (float)hh);
  size_t o = ((size_t)b * HALF + (r >> 1)) * 256 + t;
  if (r & 1) {
    bnh[o] = hh;
    bnl[o] = ll;
  } else {
    anh[o] = hh;
    anl[o] = ll;
  }
}

// ---------------------------------------------------------------------------
// Fused: reduce 16 argmax partials per row (-> best_b) + stable descending
// bitonic argsort of the 1024 best scores per batch. 512 threads.
// ---------------------------------------------------------------------------
__global__ __launch_bounds__(512) void sort_desc(
    const float* __restrict__ sval, const int* __restrict__ sidx,
    int* __restrict__ best_b, int* __restrict__ order) {
  const int b = blockIdx.x;
  __shared__ float sv[1024];
  __shared__ int si[1024];
  for (int i = threadIdx.x; i < 1024; i += 512) {
    const size_t base = ((size_t)b * HALF + i) * 16;
    float bv = sval[base];
    int bc = sidx[base];
#pragma unroll
    for (int e = 1; e < 16; ++e) {
      float v = sval[base + e];
      int c = sidx[base + e];
      if (v > bv || (v == bv && c < bc)) { bv = v; bc = c; }
    }
    sv[i] = bv;
    si[i] = i;
    best_b[b * HALF + i] = bc;
  }
  __syncthreads();
  for (int k = 2; k <= 1024; k <<= 1) {
    for (int j = k >> 1; j > 0; j >>= 1) {
      for (int t = threadIdx.x; t < 1024; t += 512) {
        int ixj = t ^ j;
        if (ixj > t) {
          bool dir = ((t & k) == 0);
          float va = sv[t], vb = sv[ixj];
          int ia = si[t], ib = si[ixj];
          bool before = (vb > va) || (vb == va && ib < ia);
          if (before == dir) {
            sv[t] = vb; sv[ixj] = va;
            si[t] = ib; si[ixj] = ia;
          }
        }
      }
      __syncthreads();
    }
  }
  for (int i = threadIdx.x; i < 1024; i += 512) order[b * HALF + i] = si[i];
}

// ---------------------------------------------------------------------------
// Parallel greedy selection (exact serial-scan equivalent) + index maps.
// ---------------------------------------------------------------------------
__global__ __launch_bounds__(256) void select_and_index(
    const int* __restrict__ best_b, const int* __restrict__ order,
    int* __restrict__ keep_idx, int* __restrict__ partner,
    int* __restrict__ dst2) {
  const int b = blockIdx.x;
  __shared__ int rankA[HALF];
  __shared__ int minrank[HALF];
  __shared__ int taken[HALF];
  __shared__ int sel_a[RR], sel_b[RR];
  __shared__ int removed[NN];
  __shared__ int src_row[NN];
  __shared__ int tsum[256];
  const int t = threadIdx.x;

  for (int i = t; i < HALF; i += 256) { minrank[i] = 0x7fffffff; taken[i] = 0; }
  for (int i = t; i < NN; i += 256) {
    removed[i] = 0;
    partner[b * NN + i] = -1;
  }
  for (int i = t; i < NM; i += 256) dst2[b * NM + i] = -1;
  __syncthreads();
  int ord[4];
#pragma unroll
  for (int q = 0; q < 4; ++q) {
    int step = t * 4 + q;
    ord[q] = order[b * HALF + step];
    rankA[ord[q]] = step;
  }
  __syncthreads();
#pragma unroll
  for (int q = 0; q < 4; ++q) {
    int a = t * 4 + q;
    atomicMin(&minrank[best_b[b * HALF + a]], rankA[a]);
  }
  __syncthreads();
  for (int i = t; i < HALF; i += 256) {
    int mr = minrank[i];
    if (mr != 0x7fffffff) taken[mr] = 1;
  }
  __syncthreads();
  int c[4];
  int mysum = 0;
#pragma unroll
  for (int q = 0; q < 4; ++q) { c[q] = taken[t * 4 + q]; mysum += c[q]; }
  tsum[t] = mysum;
  __syncthreads();
  for (int off = 1; off < 256; off <<= 1) {
    int v = (t >= off) ? tsum[t - off] : 0;
    __syncthreads();
    tsum[t] += v;
    __syncthreads();
  }
  int run = tsum[t] - mysum;
#pragma unroll
  for (int q = 0; q < 4; ++q) {
    if (c[q] && run < RR) {
      int a = ord[q];
      sel_a[run] = 2 * a;
      sel_b[run] = 2 * best_b[b * HALF + a] + 1;
    }
    run += c[q];
  }
  __syncthreads();
  const int cnt = min(tsum[255], RR);
  if (t >= cnt) { sel_a[t] = sel_a[0]; sel_b[t] = sel_b[0]; }
  __syncthreads();
  {
    int ga = sel_a[t], gb = sel_b[t];
    removed[gb] = 1;
    partner[b * NN + ga] = gb;
  }
  __syncthreads();
  int myc = 0;
#pragma unroll
  for (int q = 0; q < 8; ++q) myc += !removed[8 * t + q];
  tsum[t] = myc;
  __syncthreads();
  for (int off = 1; off < 256; off <<= 1) {
    int v = (t >= off) ? tsum[t - off] : 0;
    __syncthreads();
    tsum[t] += v;
    __syncthreads();
  }
  int pos = tsum[t] - myc;
#pragma unroll
  for (int q = 0; q < 8; ++q) {
    int p = 8 * t + q;
    int sr = -1;
    if (!removed[p]) {
      if (pos < NM) {
        keep_idx[b * NM + pos] = p;
        sr = pos;
      }
      ++pos;
    }
    src_row[p] = sr;
  }
  __syncthreads();
  {
    int sr = src_row[sel_a[t]];
    dst2[b * NM + sr] = sel_b[t];
  }
}

// ---------------------------------------------------------------------------
// Merge -> bf16 x_mb
// ---------------------------------------------------------------------------
__global__ __launch_bounds__(256) void merge_kernel(
    const float* __restrict__ x, const int* __restrict__ keep_idx,
    const int* __restrict__ partner, __bf16* __restrict__ x_mb) {
  const int mrow = blockIdx.x;
  const int b = mrow / NM;
  const int t = mrow % NM;
  const int p = keep_idx[b * NM + t];
  const int pp = partner[b * NN + p];
  const float4* src =
      reinterpret_cast<const float4*>(x + ((size_t)b * NN + p) * DM);
  float4 val = src[threadIdx.x];
  if (pp >= 0) {
    const float4* s2 =
        reinterpret_cast<const float4*>(x + ((size_t)b * NN + pp) * DM);
    float4 v2 = s2[threadIdx.x];
    val.x = 0.5f * (val.x + v2.x);
    val.y = 0.5f * (val.y + v2.y);
    val.z = 0.5f * (val.z + v2.z);
    val.w = 0.5f * (val.w + v2.w);
  }
  union { __bf16 h[4]; uint2 u; } U;
  U.h[0] = (__bf16)val.x;
  U.h[1] = (__bf16)val.y;
  U.h[2] = (__bf16)val.z;
  U.h[3] = (__bf16)val.w;
  ((uint2*)(x_mb + (size_t)mrow * DM))[threadIdx.x] = U.u;
}

// ---------------------------------------------------------------------------
// Fused QKV post-processing: z < BB*NM -> RoPE q+k repack; else V transpose.
// ---------------------------------------------------------------------------
__global__ __launch_bounds__(256) void prep_qkv(
    const float* __restrict__ qkv, const float* __restrict__ fc,
    __bf16* __restrict__ qbh, __bf16* __restrict__ kbh,
    __bf16* __restrict__ vtb) {
  __shared__ float ld[64][65];
  const int z = blockIdx.x;
  if (z < BB * NM) {
    const int row = z;
    const int t = row % NM;
    const int b = row / NM;
    for (int idx = threadIdx.x; idx < 640; idx += 256) {
      int u = idx & 31;
      float c = fc[(t * 32 + u) * 2];
      float s = fc[(t * 32 + u) * 2 + 1];
      if (idx < 512) {
        int h = idx >> 5;
        const float* p = qkv + (size_t)row * 1536 + h * 64 + 2 * u;
        float x1 = p[0], x2 = p[1];
        __bf16* d = qbh + ((size_t)(b * NH + h) * NM + t) * 64 + 2 * u;
        d[0] = (__bf16)((x1 * c - x2 * s) * 0.125f);
        d[1] = (__bf16)((x1 * s + x2 * c) * 0.125f);
      } else {
        int h = (idx - 512) >> 5;
        const float* p = qkv + (size_t)row * 1536 + 1024 + h * 64 + 2 * u;
        float x1 = p[0], x2 = p[1];
        __bf16* d = kbh + ((size_t)(b * NKV + h) * NM + t) * 64 + 2 * u;
        d[0] = (__bf16)(x1 * c - x2 * s);
        d[1] = (__bf16)(x1 * s + x2 * c);
      }
    }
    return;
  }
  int bid = z - BB * NM;
  const int kt = bid % (NM / 64); bid /= (NM / 64);
  const int kvh = bid % NKV;
  const int b = bid / NKV;
  const int j0 = kt * 64;
  for (int t2 = threadIdx.x; t2 < 1024; t2 += 256) {
    int key = t2 >> 4, c4 = t2 & 15;
    float4 v4 = *reinterpret_cast<const float4*>(
        qkv + (size_t)(b * NM + j0 + key) * 1536 + 1280 + kvh * 64 + c4 * 4);
    ld[key][c4 * 4 + 0] = v4.x;
    ld[key][c4 * 4 + 1] = v4.y;
    ld[key][c4 * 4 + 2] = v4.z;
    ld[key][c4 * 4 + 3] = v4.w;
  }
  __syncthreads();
  const int dim = threadIdx.x >> 2, kc = threadIdx.x & 3;
  __bf16* out = vtb + ((size_t)(b * NKV + kvh) * 64 + dim) * NM + j0 + kc * 16;
#pragma unroll
  for (int kk = 0; kk < 16; ++kk) out[kk] = (__bf16)ld[kc * 16 + kk][dim];
}

// ---------------------------------------------------------------------------
// Flash attention, bf16 MFMA, S^T orientation, fixed-shift softmax,
// split-K over NSPL=4, 8-wave blocks, single-buffer async K/V.
// P routed through padded PER-WAVE LDS (4 ds_write_b64 + 2 ds_read_b128).
// ---------------------------------------------------------------------------
#define LDP 72  // padded P row stride (bf16): 2-way bank alias only (free)

__global__ __launch_bounds__(512) void attn_mfma(
    const __bf16* __restrict__ qbh, const __bf16* __restrict__ kbh,
    const __bf16* __restrict__ vtb, float* __restrict__ pl,
    __bf16* __restrict__ pacc) {
  __shared__ __align__(16) __bf16 Ks[4096];
  __shared__ __align__(16) __bf16 Vs[4096];
  __shared__ __align__(16) __bf16 Pt[8 * 16 * LDP];
  int bid = blockIdx.x;
  const int qt2 = bid % (NM / 32); bid /= (NM / 32);
  const int split = bid % NSPL; bid /= NSPL;
  const int kvh = bid % NKV;
  const int b = bid / NKV;
  const int w = threadIdx.x >> 6;
  const int lane = threadIdx.x & 63;
  const int h = kvh * 4 + (w & 3);
  const int qt = qt2 * 32 + (w >> 2) * 16;
  const int g = lane >> 4;
  const int ml = lane & 15;
  __bf16* Pw = Pt + w * 16 * LDP;

  const __bf16* qrow = qbh + ((size_t)(b * NH + h) * NM + qt + ml) * 64;
  bf16x8 qa0 = *reinterpret_cast<const bf16x8*>(qrow + g * 8);
  bf16x8 qa1 = *reinterpret_cast<const bf16x8*>(qrow + 32 + g * 8);

  f32x4 acc[4];
#pragma unroll
  for (int mt = 0; mt < 4; ++mt) acc[mt] = (f32x4){0.f, 0.f, 0.f, 0.f};
  float lsum = 0.f;

  const __bf16* kp = kbh + (size_t)(b * NKV + kvh) * NM * 64;
  const __bf16* vp = vtb + (size_t)(b * NKV + kvh) * 64 * NM;

  const int jt0 = split * (NT / NSPL);
  for (int jt = jt0; jt < jt0 + NT / NSPL; ++jt) {
    __syncthreads();
    {
      const int c = threadIdx.x;  // 512 chunks each for Ks and Vs
      const int lb = w * 512;
      async16(kp + (size_t)(jt * 64 + ((c >> 7) << 4) + (c & 15)) * 64 +
                  (((c >> 6) & 1) << 5) + (((c >> 4) & 3) << 3),
              &Ks[lb]);
      async16(vp + (size_t)(((c >> 7) << 4) + (c & 15)) * NM + jt * 64 +
                  (((c >> 6) & 1) << 5) + (((c >> 4) & 3) << 3),
              &Vs[lb]);
    }
    __syncthreads();
    f32x4 S[4];
#pragma unroll
    for (int nt = 0; nt < 4; ++nt) {
      bf16x8 k0 = *(const bf16x8*)&Ks[(nt * 128 + lane) * 8];
      bf16x8 k1 = *(const bf16x8*)&Ks[(nt * 128 + 64 + lane) * 8];
      f32x4 s4 = (f32x4){0.f, 0.f, 0.f, 0.f};
      s4 = __builtin_amdgcn_mfma_f32_16x16x32_bf16(k0, qa0, s4, 0, 0, 0);
      s4 = __builtin_amdgcn_mfma_f32_16x16x32_bf16(k1, qa1, s4, 0, 0, 0);
      S[nt] = s4;
    }
#pragma unroll
    for (int nt = 0; nt < 4; ++nt) {
      float p0 = __expf(S[nt][0]);
      float p1 = __expf(S[nt][1]);
      float p2 = __expf(S[nt][2]);
      float p3 = __expf(S[nt][3]);
      lsum += (p0 + p1) + (p2 + p3);
      uint2 u;
      u.x = pk2(p0, p1);
      u.y = pk2(p2, p3);
      *reinterpret_cast<uint2*>(&Pw[ml * LDP + nt * 16 + g * 4]) = u;
    }
    bf16x8 P0 = *(const bf16x8*)&Pw[ml * LDP + g * 8];
    bf16x8 P1 = *(const bf16x8*)&Pw[ml * LDP + 32 + g * 8];
#pragma unroll
    for (int mt = 0; mt < 4; ++mt) {
      bf16x8 v0 = *(const bf16x8*)&Vs[(mt * 128 + lane) * 8];
      bf16x8 v1 = *(const bf16x8*)&Vs[(mt * 128 + 64 + lane) * 8];
      acc[mt] = __builtin_amdgcn_mfma_f32_16x16x32_bf16(v0, P0, acc[mt], 0, 0, 0);
      acc[mt] = __builtin_amdgcn_mfma_f32_16x16x32_bf16(v1, P1, acc[mt], 0, 0, 0);
    }
  }
  lsum += __shfl_xor(lsum, 16, 64);
  lsum += __shfl_xor(lsum, 32, 64);
  const size_t row = (size_t)(b * NH + h) * NM + qt + ml;
  if (g == 0) pl[row * NSPL + split] = lsum;
  __bf16* pa = pacc + (row * NSPL + split) * 64;
#pragma unroll
  for (int mt = 0; mt < 4; ++mt) {
    uint2 u;
    u.x = pk2(acc[mt][0], acc[mt][1]);
    u.y = pk2(acc[mt][2], acc[mt][3]);
    *reinterpret_cast<uint2*>(pa + mt * 16 + g * 4) = u;
  }
}

// ---------------------------------------------------------------------------
// Split-K combine (fixed shift: plain sums) -> bf16 attn_ob
// ---------------------------------------------------------------------------
__global__ __launch_bounds__(256) void attn_combine(
    const float* __restrict__ pl, const __bf16* __restrict__ pacc,
    __bf16* __restrict__ attn_ob) {
  const size_t rid = (size_t)blockIdx.x * 4 + (threadIdx.x >> 6);
  const int d = threadIdx.x & 63;
  float num = 0.f, den = 0.f;
#pragma unroll
  for (int s = 0; s < NSPL; ++s) {
    num += (float)pacc[(rid * NSPL + s) * 64 + d];
    den += pl[rid * NSPL + s];
  }
  float o = num / den;
  const int q = (int)(rid % NM);
  const int h = (int)((rid / NM) % NH);
  const int b = (int)(rid / ((size_t)NM * NH));
  attn_ob[((size_t)(b * NM + q)) * DM + h * 64 + d] = (__bf16)o;
}

// ---------------------------------------------------------------------------
extern "C" void kernel_launch(void* const* d_in, const int* in_sizes, int n_in,
                              void* d_out, int out_size, void* d_ws,
                              size_t ws_size, hipStream_t stream) {
  const float* x = (const float*)d_in[0];
  const float* fc = (const float*)d_in[1];
  const float* Wq = (const float*)d_in[2];
  const float* Wk = (const float*)d_in[3];
  const float* Wv = (const float*)d_in[4];
  const float* Wo = (const float*)d_in[5];
  float* out = (float*)d_out;

  char* ws = (char*)d_ws;
  size_t off = 0;
  auto alloc = [&](size_t bytes) {
    void* p = ws + off;
    off += (bytes + 255) & ~(size_t)255;
    return p;
  };
  float* metric0 = (float*)alloc((size_t)BB * NN * 256 * 4);
  float* metric1 = (float*)alloc((size_t)BB * NN * 256 * 4);
  float* metric2 = (float*)alloc((size_t)BB * NN * 256 * 4);
  float* metric3 = (float*)alloc((size_t)BB * NN * 256 * 4);
  int* best_b = (int*)alloc((size_t)BB * HALF * 4);
  int* order = (int*)alloc((size_t)BB * HALF * 4);
  int* keep_idx = (int*)alloc((size_t)BB * NM * 4);
  int* partner = (int*)alloc((size_t)BB * NN * 4);
  int* dst2 = (int*)alloc((size_t)BB * NM * 4);
  float* sval = (float*)alloc((size_t)BB * HALF * 16 * 4);
  int* sidx = (int*)alloc((size_t)BB * HALF * 16 * 4);
  char* bigreg = (char*)alloc((size_t)30 * 1024 * 1024);
  __bf16* xh = (__bf16*)bigreg;
  __bf16* xl = (__bf16*)(bigreg + (size_t)8704 * 1024);
  __bf16* anh = (__bf16*)bigreg;
  __bf16* anl = (__bf16*)(bigreg + (size_t)1100 * 1024);
  __bf16* bnh = (__bf16*)(bigreg + (size_t)2200 * 1024);
  __bf16* bnl = (__bf16*)(bigreg + (size_t)3300 * 1024);
  float* qkv = (float*)bigreg;
  __bf16* pacc = (__bf16*)bigreg;
  __bf16* x_mb = (__bf16*)alloc((size_t)BB * NM * DM * 2);
  __bf16* qbh = (__bf16*)alloc((size_t)BB * NH * NM * 64 * 2);
  __bf16* kbh = (__bf16*)alloc((size_t)BB * NKV * NM * 64 * 2);
  __bf16* vtb = (__bf16*)alloc((size_t)BB * NKV * 64 * NM * 2);
  __bf16* attn_ob = (__bf16*)alloc((size_t)BB * NM * DM * 2);
  float* pl = (float*)alloc((size_t)BB * NH * NM * NSPL * 4);
  __bf16* Wqkvt = (__bf16*)alloc((size_t)1536 * DM * 2);
  __bf16* Wktl = (__bf16*)alloc((size_t)256 * DM * 2);
  __bf16* Wot = (__bf16*)alloc((size_t)DM * DM * 2);
  const __bf16* Wkth = Wqkvt + (size_t)1024 * 1024;

  // ---- fused prep: weight transposes + x hi/lo split
  prep_in<<<640 + (BB * NN * DM / 4) / 256, 256, 0, stream>>>(
      Wq, Wk, Wv, Wo, x, Wqkvt, Wktl, Wot, xh, xl);
  // ---- metric = x @ Wk (3-term hi/lo MFMA, 128-row tiles, split-K x4)
  gemm3t<<<dim3(32, 4, 4), 256, 0, stream>>>(xh, xl, Wkth, Wktl, metric0,
                                             metric1, metric2, metric3,
                                             BB * NN, 256, DM);
  normalize_split<<<BB * NN, 256, 0, stream>>>(metric0, metric1, metric2,
                                               metric3, anh, anl, bnh, bnl);
  gemm_scam<<<dim3(16, 16, 2), 256, 0, stream>>>(anh, anl, bnh, bnl, sval,
                                                 sidx);
  // ---- fused argmax-reduce + sort
  sort_desc<<<BB, 512, 0, stream>>>(sval, sidx, best_b, order);
  select_and_index<<<BB, 256, 0, stream>>>(best_b, order, keep_idx, partner,
                                           dst2);
  merge_kernel<<<BB * NM, 256, 0, stream>>>(x, keep_idx, partner, x_mb);
  // ---- fused QKV projection
  gemm_bf16<<<dim3(28, 24), 256, 0, stream>>>(x_mb, Wqkvt, qkv, BB * NM, 1536,
                                              DM);
  // ---- fused RoPE + V repack
  prep_qkv<<<BB * NM + BB * NKV * (NM / 64), 256, 0, stream>>>(qkv, fc, qbh,
                                                               kbh, vtb);
  // ---- attention (512-thr blocks, split-K x4, LDS-P) + combine
  attn_mfma<<<BB * NKV * NSPL * (NM / 32), 512, 0, stream>>>(qbh, kbh, vtb, pl,
                                                             pacc);
  attn_combine<<<(BB * NH * NM) / 4, 256, 0, stream>>>(pl, pacc, attn_ob);
  // ---- output projection with fused unmerge scatter
  gemm_wo<<<dim3(28, 16), 256, 0, stream>>>(attn_ob, Wot, keep_idx, dst2, out,
                                            BB * NM, DM, DM);
}

// Round 15
// 280.614 us; speedup vs baseline: 1.0723x; 1.0175x over previous
//
#include <hip/hip_runtime.h>
#include <hip/hip_bf16.h>
#include <math.h>

// Problem constants
#define BB 2
#define NN 2048
#define DM 1024
#define NH 16
#define NKV 4
#define HD 64
#define RR 256
#define HALF 1024
#define NM 1792   // NN - RR
#define NT 28     // key tiles of 64
#define NSPL 4    // attention split-K

typedef __bf16 bf16x8 __attribute__((ext_vector_type(8)));
typedef float f32x4 __attribute__((ext_vector_type(4)));

__device__ inline unsigned pk2(float a, float b) {
  union { __bf16 h; unsigned short u; } ua, ub;
  ua.h = (__bf16)a;
  ub.h = (__bf16)b;
  return (unsigned)ua.u | ((unsigned)ub.u << 16);
}

// Async global->LDS, 16B per lane. LDS dest = wave-uniform base + lane*16.
__device__ __forceinline__ void async16(const void* g, void* l) {
  __builtin_amdgcn_global_load_lds(
      (const __attribute__((address_space(1))) void*)g,
      (__attribute__((address_space(3))) void*)l, 16, 0, 0);
}

// ---------------------------------------------------------------------------
// Fused QKV GEMM: C = x_mb @ Wqkvt^T (128x64 tiles) with epilogue that
// applies RoPE to Q/K (one shfl_xor(.,1) for the rotation partner; 64-col
// blocks are entirely Q, K, or V so branches are block-uniform) and writes
// qbh/kbh head-major bf16; V columns are written transposed into vtb
// (4 consecutive tokens per lane pack into one uint2).
// ---------------------------------------------------------------------------
__global__ __launch_bounds__(256) void gemm_qkv(
    const __bf16* __restrict__ A, const __bf16* __restrict__ Bt,
    const float* __restrict__ fc, __bf16* __restrict__ qbh,
    __bf16* __restrict__ kbh, __bf16* __restrict__ vtb, int M, int N, int K) {
  __shared__ __align__(16) __bf16 As[8192];  // 128 x 64
  __shared__ __align__(16) __bf16 Bs[4096];  // 64 x 64
  const int bm0 = blockIdx.x * 128;
  const int bn0 = blockIdx.y * 64;
  const int w = threadIdx.x >> 6;
  const int lane = threadIdx.x & 63;
  f32x4 acc[2][4];
#pragma unroll
  for (int i = 0; i < 2; ++i)
#pragma unroll
    for (int nt = 0; nt < 4; ++nt) acc[i][nt] = (f32x4){0.f, 0.f, 0.f, 0.f};
  for (int kk = 0; kk < K; kk += 64) {
    __syncthreads();
#pragma unroll
    for (int it = 0; it < 4; ++it) {
      const int c = it * 256 + w * 64 + lane;
      async16(A + (size_t)(bm0 + ((c >> 7) << 4) + (c & 15)) * K + kk +
                  (((c >> 6) & 1) << 5) + (((c >> 4) & 3) << 3),
              &As[(it * 256 + w * 64) * 8]);
    }
#pragma unroll
    for (int it = 0; it < 2; ++it) {
      const int c = it * 256 + w * 64 + lane;
      async16(Bt + (size_t)(bn0 + ((c >> 7) << 4) + (c & 15)) * K + kk +
                  (((c >> 6) & 1) << 5) + (((c >> 4) & 3) << 3),
              &Bs[(it * 256 + w * 64) * 8]);
    }
    __syncthreads();
#pragma unroll
    for (int s = 0; s < 2; ++s) {
      bf16x8 a0 = *(const bf16x8*)&As[((2 * w) * 128 + s * 64 + lane) * 8];
      bf16x8 a1 = *(const bf16x8*)&As[((2 * w + 1) * 128 + s * 64 + lane) * 8];
#pragma unroll
      for (int nt = 0; nt < 4; ++nt) {
        bf16x8 bfr = *(const bf16x8*)&Bs[(nt * 128 + s * 64 + lane) * 8];
        acc[0][nt] =
            __builtin_amdgcn_mfma_f32_16x16x32_bf16(a0, bfr, acc[0][nt], 0, 0, 0);
        acc[1][nt] =
            __builtin_amdgcn_mfma_f32_16x16x32_bf16(a1, bfr, acc[1][nt], 0, 0, 0);
      }
    }
  }
  const int g = lane >> 4, ml = lane & 15;
#pragma unroll
  for (int i = 0; i < 2; ++i) {
    const int row0 = bm0 + (2 * w + i) * 16 + g * 4;
    const int b = row0 >= NM;
    const int t0 = row0 - b * NM;
#pragma unroll
    for (int nt = 0; nt < 4; ++nt) {
      const int col = bn0 + nt * 16 + ml;
      if (col < 1024) {  // Q: RoPE + scale, head-major
        const int h = col >> 6, d = col & 63, u = d >> 1;
#pragma unroll
        for (int r = 0; r < 4; ++r) {
          const int t = t0 + r;
          float2 cs = *(const float2*)(fc + (t * 32 + u) * 2);
          float self = acc[i][nt][r];
          float other = __shfl_xor(self, 1, 64);
          float ro = (d & 1) ? (other * cs.y + self * cs.x)
                             : (self * cs.x - other * cs.y);
          qbh[((size_t)(b * NH + h) * NM + t) * 64 + d] = (__bf16)(ro * 0.125f);
        }
      } else if (col < 1280) {  // K: RoPE, head-major
        const int kvh = (col - 1024) >> 6, d = col & 63, u = d >> 1;
#pragma unroll
        for (int r = 0; r < 4; ++r) {
          const int t = t0 + r;
          float2 cs = *(const float2*)(fc + (t * 32 + u) * 2);
          float self = acc[i][nt][r];
          float other = __shfl_xor(self, 1, 64);
          float ro = (d & 1) ? (other * cs.y + self * cs.x)
                             : (self * cs.x - other * cs.y);
          kbh[((size_t)(b * NKV + kvh) * NM + t) * 64 + d] = (__bf16)ro;
        }
      } else {  // V: transposed [dim][key], 4 consecutive tokens per lane
        const int kvh = (col - 1280) >> 6, d = col & 63;
        uint2 u2;
        u2.x = pk2(acc[i][nt][0], acc[i][nt][1]);
        u2.y = pk2(acc[i][nt][2], acc[i][nt][3]);
        *(uint2*)(vtb + ((size_t)(b * NKV + kvh) * 64 + d) * NM + t0) = u2;
      }
    }
  }
}

// ---------------------------------------------------------------------------
// Wo GEMM (128x64 tiles, async staging) with fused unmerge-scatter epilogue.
// ---------------------------------------------------------------------------
__global__ __launch_bounds__(256) void gemm_wo(
    const __bf16* __restrict__ A, const __bf16* __restrict__ Bt,
    const int* __restrict__ keep_idx, const int* __restrict__ dst2,
    float* __restrict__ out, int M, int N, int K) {
  __shared__ __align__(16) __bf16 As[8192];
  __shared__ __align__(16) __bf16 Bs[4096];
  const int bm0 = blockIdx.x * 128;
  const int bn0 = blockIdx.y * 64;
  const int w = threadIdx.x >> 6;
  const int lane = threadIdx.x & 63;
  f32x4 acc[2][4];
#pragma unroll
  for (int i = 0; i < 2; ++i)
#pragma unroll
    for (int nt = 0; nt < 4; ++nt) acc[i][nt] = (f32x4){0.f, 0.f, 0.f, 0.f};
  for (int kk = 0; kk < K; kk += 64) {
    __syncthreads();
#pragma unroll
    for (int it = 0; it < 4; ++it) {
      const int c = it * 256 + w * 64 + lane;
      async16(A + (size_t)(bm0 + ((c >> 7) << 4) + (c & 15)) * K + kk +
                  (((c >> 6) & 1) << 5) + (((c >> 4) & 3) << 3),
              &As[(it * 256 + w * 64) * 8]);
    }
#pragma unroll
    for (int it = 0; it < 2; ++it) {
      const int c = it * 256 + w * 64 + lane;
      async16(Bt + (size_t)(bn0 + ((c >> 7) << 4) + (c & 15)) * K + kk +
                  (((c >> 6) & 1) << 5) + (((c >> 4) & 3) << 3),
              &Bs[(it * 256 + w * 64) * 8]);
    }
    __syncthreads();
#pragma unroll
    for (int s = 0; s < 2; ++s) {
      bf16x8 a0 = *(const bf16x8*)&As[((2 * w) * 128 + s * 64 + lane) * 8];
      bf16x8 a1 = *(const bf16x8*)&As[((2 * w + 1) * 128 + s * 64 + lane) * 8];
#pragma unroll
      for (int nt = 0; nt < 4; ++nt) {
        bf16x8 bfr = *(const bf16x8*)&Bs[(nt * 128 + s * 64 + lane) * 8];
        acc[0][nt] =
            __builtin_amdgcn_mfma_f32_16x16x32_bf16(a0, bfr, acc[0][nt], 0, 0, 0);
        acc[1][nt] =
            __builtin_amdgcn_mfma_f32_16x16x32_bf16(a1, bfr, acc[1][nt], 0, 0, 0);
      }
    }
  }
  const int g = lane >> 4, ml = lane & 15;
#pragma unroll
  for (int i = 0; i < 2; ++i)
#pragma unroll
    for (int r = 0; r < 4; ++r) {
      const int row = bm0 + (2 * w + i) * 16 + g * 4 + r;
      const int bb = row / NM, tt = row % NM;
      const int p1 = keep_idx[bb * NM + tt];
      const int p2 = dst2[bb * NM + tt];
#pragma unroll
      for (int nt = 0; nt < 4; ++nt) {
        const int col = bn0 + nt * 16 + ml;
        float v = acc[i][nt][r];
        out[((size_t)(bb * NN + p1)) * DM + col] = v;
        if (p2 >= 0) out[((size_t)(bb * NN + p2)) * DM + col] = v;
      }
    }
}

// ---------------------------------------------------------------------------
// 3-term hi/lo MFMA GEMM (fp32-accurate), async staging, 128x64 block tile.
// Split-K x4 via blockIdx.z -> separate outputs C0..C3.
// ---------------------------------------------------------------------------
__global__ __launch_bounds__(256) void gemm3t(
    const __bf16* __restrict__ Ah, const __bf16* __restrict__ Al,
    const __bf16* __restrict__ Bh, const __bf16* __restrict__ Bl,
    float* __restrict__ C0, float* __restrict__ C1, float* __restrict__ C2,
    float* __restrict__ C3, int M, int N, int K) {
  __shared__ __align__(16) __bf16 Ahs[8192], Als[8192];
  __shared__ __align__(16) __bf16 Bhs[4096], Bls[4096];
  const int z = blockIdx.z;
  float* C = (z == 0) ? C0 : (z == 1) ? C1 : (z == 2) ? C2 : C3;
  const int kof = z * (K / 4);
  const int bm0 = blockIdx.x * 128;
  const int bn0 = blockIdx.y * 64;
  const int w = threadIdx.x >> 6;
  const int lane = threadIdx.x & 63;
  f32x4 acc[2][4];
#pragma unroll
  for (int i = 0; i < 2; ++i)
#pragma unroll
    for (int nt = 0; nt < 4; ++nt) acc[i][nt] = (f32x4){0.f, 0.f, 0.f, 0.f};
  for (int kk = kof; kk < kof + K / 4; kk += 64) {
    __syncthreads();
#pragma unroll
    for (int it = 0; it < 4; ++it) {
      const int c = it * 256 + w * 64 + lane;
      const size_t ra = (size_t)(bm0 + ((c >> 7) << 4) + (c & 15)) * K;
      const int col = kk + (((c >> 6) & 1) << 5) + (((c >> 4) & 3) << 3);
      const int lb = (it * 256 + w * 64) * 8;
      async16(Ah + ra + col, &Ahs[lb]);
      async16(Al + ra + col, &Als[lb]);
    }
#pragma unroll
    for (int it = 0; it < 2; ++it) {
      const int c = it * 256 + w * 64 + lane;
      const size_t rb = (size_t)(bn0 + ((c >> 7) << 4) + (c & 15)) * K;
      const int col = kk + (((c >> 6) & 1) << 5) + (((c >> 4) & 3) << 3);
      const int lb = (it * 256 + w * 64) * 8;
      async16(Bh + rb + col, &Bhs[lb]);
      async16(Bl + rb + col, &Bls[lb]);
    }
    __syncthreads();
#pragma unroll
    for (int s = 0; s < 2; ++s) {
      bf16x8 ah0 = *(const bf16x8*)&Ahs[((2 * w) * 128 + s * 64 + lane) * 8];
      bf16x8 ah1 = *(const bf16x8*)&Ahs[((2 * w + 1) * 128 + s * 64 + lane) * 8];
      bf16x8 al0 = *(const bf16x8*)&Als[((2 * w) * 128 + s * 64 + lane) * 8];
      bf16x8 al1 = *(const bf16x8*)&Als[((2 * w + 1) * 128 + s * 64 + lane) * 8];
#pragma unroll
      for (int nt = 0; nt < 4; ++nt) {
        bf16x8 bh = *(const bf16x8*)&Bhs[(nt * 128 + s * 64 + lane) * 8];
        bf16x8 bl = *(const bf16x8*)&Bls[(nt * 128 + s * 64 + lane) * 8];
        acc[0][nt] = __builtin_amdgcn_mfma_f32_16x16x32_bf16(al0, bh, acc[0][nt], 0, 0, 0);
        acc[0][nt] = __builtin_amdgcn_mfma_f32_16x16x32_bf16(ah0, bl, acc[0][nt], 0, 0, 0);
        acc[0][nt] = __builtin_amdgcn_mfma_f32_16x16x32_bf16(ah0, bh, acc[0][nt], 0, 0, 0);
        acc[1][nt] = __builtin_amdgcn_mfma_f32_16x16x32_bf16(al1, bh, acc[1][nt], 0, 0, 0);
        acc[1][nt] = __builtin_amdgcn_mfma_f32_16x16x32_bf16(ah1, bl, acc[1][nt], 0, 0, 0);
        acc[1][nt] = __builtin_amdgcn_mfma_f32_16x16x32_bf16(ah1, bh, acc[1][nt], 0, 0, 0);
      }
    }
  }
  const int g = lane >> 4, ml = lane & 15;
#pragma unroll
  for (int i = 0; i < 2; ++i)
#pragma unroll
    for (int nt = 0; nt < 4; ++nt)
#pragma unroll
      for (int r = 0; r < 4; ++r)
        C[(size_t)(bm0 + (2 * w + i) * 16 + g * 4 + r) * N + bn0 + nt * 16 +
          ml] = acc[i][nt][r];
}

// ---------------------------------------------------------------------------
// Scores 3-term GEMM, 128x64 tiles, fused per-tile row-argmax epilogue.
// ---------------------------------------------------------------------------
__global__ __launch_bounds__(256) void gemm_scam(
    const __bf16* __restrict__ Ah, const __bf16* __restrict__ Al,
    const __bf16* __restrict__ Bh, const __bf16* __restrict__ Bl,
    float* __restrict__ sval, int* __restrict__ sidx) {
  __shared__ __align__(16) __bf16 Ahs[8192], Als[8192];
  __shared__ __align__(16) __bf16 Bhs[4096], Bls[4096];
  const size_t zo = (size_t)blockIdx.z * HALF * 256;
  const int bm0 = blockIdx.x * 128;
  const int bn0 = blockIdx.y * 64;
  const int w = threadIdx.x >> 6;
  const int lane = threadIdx.x & 63;
  f32x4 acc[2][4];
#pragma unroll
  for (int i = 0; i < 2; ++i)
#pragma unroll
    for (int nt = 0; nt < 4; ++nt) acc[i][nt] = (f32x4){0.f, 0.f, 0.f, 0.f};
  for (int kk = 0; kk < 256; kk += 64) {
    __syncthreads();
#pragma unroll
    for (int it = 0; it < 4; ++it) {
      const int c = it * 256 + w * 64 + lane;
      const size_t ra = zo + (size_t)(bm0 + ((c >> 7) << 4) + (c & 15)) * 256;
      const int col = kk + (((c >> 6) & 1) << 5) + (((c >> 4) & 3) << 3);
      const int lb = (it * 256 + w * 64) * 8;
      async16(Ah + ra + col, &Ahs[lb]);
      async16(Al + ra + col, &Als[lb]);
    }
#pragma unroll
    for (int it = 0; it < 2; ++it) {
      const int c = it * 256 + w * 64 + lane;
      const size_t rb = zo + (size_t)(bn0 + ((c >> 7) << 4) + (c & 15)) * 256;
      const int col = kk + (((c >> 6) & 1) << 5) + (((c >> 4) & 3) << 3);
      const int lb = (it * 256 + w * 64) * 8;
      async16(Bh + rb + col, &Bhs[lb]);
      async16(Bl + rb + col, &Bls[lb]);
    }
    __syncthreads();
#pragma unroll
    for (int s = 0; s < 2; ++s) {
      bf16x8 ah0 = *(const bf16x8*)&Ahs[((2 * w) * 128 + s * 64 + lane) * 8];
      bf16x8 ah1 = *(const bf16x8*)&Ahs[((2 * w + 1) * 128 + s * 64 + lane) * 8];
      bf16x8 al0 = *(const bf16x8*)&Als[((2 * w) * 128 + s * 64 + lane) * 8];
      bf16x8 al1 = *(const bf16x8*)&Als[((2 * w + 1) * 128 + s * 64 + lane) * 8];
#pragma unroll
      for (int nt = 0; nt < 4; ++nt) {
        bf16x8 bh = *(const bf16x8*)&Bhs[(nt * 128 + s * 64 + lane) * 8];
        bf16x8 bl = *(const bf16x8*)&Bls[(nt * 128 + s * 64 + lane) * 8];
        acc[0][nt] = __builtin_amdgcn_mfma_f32_16x16x32_bf16(al0, bh, acc[0][nt], 0, 0, 0);
        acc[0][nt] = __builtin_amdgcn_mfma_f32_16x16x32_bf16(ah0, bl, acc[0][nt], 0, 0, 0);
        acc[0][nt] = __builtin_amdgcn_mfma_f32_16x16x32_bf16(ah0, bh, acc[0][nt], 0, 0, 0);
        acc[1][nt] = __builtin_amdgcn_mfma_f32_16x16x32_bf16(al1, bh, acc[1][nt], 0, 0, 0);
        acc[1][nt] = __builtin_amdgcn_mfma_f32_16x16x32_bf16(ah1, bl, acc[1][nt], 0, 0, 0);
        acc[1][nt] = __builtin_amdgcn_mfma_f32_16x16x32_bf16(ah1, bh, acc[1][nt], 0, 0, 0);
      }
    }
  }
  // epilogue: row-argmax within this 128x64 tile (ties -> lowest col)
  const int g = lane >> 4, ml = lane & 15;
#pragma unroll
  for (int i = 0; i < 2; ++i)
#pragma unroll
    for (int r = 0; r < 4; ++r) {
      float bv = acc[i][0][r];
      int bc = bn0 + ml;
#pragma unroll
      for (int nt = 1; nt < 4; ++nt) {
        float v = acc[i][nt][r];
        int c = bn0 + nt * 16 + ml;
        if (v > bv) { bv = v; bc = c; }
      }
#pragma unroll
      for (int off = 1; off < 16; off <<= 1) {
        float vo = __shfl_xor(bv, off, 64);
        int co = __shfl_xor(bc, off, 64);
        if (vo > bv || (vo == bv && co < bc)) { bv = vo; bc = co; }
      }
      if (ml == 0) {
        const int row = bm0 + (2 * w + i) * 16 + g * 4 + r;
        const size_t o = ((size_t)blockIdx.z * HALF + row) * 16 + (bn0 >> 6);
        sval[o] = bv;
        sidx[o] = bc;
      }
    }
}

// ---------------------------------------------------------------------------
// Fused input prep: z<640 -> weight transposes; z>=640 -> x hi/lo split.
// ---------------------------------------------------------------------------
__global__ __launch_bounds__(256) void prep_in(
    const float* __restrict__ Wq, const float* __restrict__ Wk,
    const float* __restrict__ Wv, const float* __restrict__ Wo,
    const float* __restrict__ x, __bf16* __restrict__ Wqkvt,
    __bf16* __restrict__ Wktl, __bf16* __restrict__ Wot,
    __bf16* __restrict__ xh, __bf16* __restrict__ xl) {
  const int z = blockIdx.x;
  if (z >= 640) {
    const int i = (z - 640) * 256 + threadIdx.x;
    float4 v = ((const float4*)x)[i];
    float f[4] = {v.x, v.y, v.z, v.w};
    union { __bf16 h[4]; uint2 u; } H, L;
#pragma unroll
    for (int j = 0; j < 4; ++j) {
      __bf16 hh = (__bf16)f[j];
      H.h[j] = hh;
      L.h[j] = (__bf16)(f[j] - (float)hh);
    }
    ((uint2*)xh)[i] = H.u;
    ((uint2*)xl)[i] = L.u;
    return;
  }
  __shared__ float ld[64][65];
  const float* src;
  __bf16* dsth;
  __bf16* dstl = nullptr;
  int N, k0, n0, rowoff;
  if (z < 256) {
    src = Wq; N = 1024; k0 = (z >> 4) << 6; n0 = (z & 15) << 6;
    dsth = Wqkvt; rowoff = 0;
  } else if (z < 320) {
    int zz = z - 256;
    src = Wk; N = 256; k0 = (zz >> 2) << 6; n0 = (zz & 3) << 6;
    dsth = Wqkvt; rowoff = 1024; dstl = Wktl;
  } else if (z < 384) {
    int zz = z - 320;
    src = Wv; N = 256; k0 = (zz >> 2) << 6; n0 = (zz & 3) << 6;
    dsth = Wqkvt; rowoff = 1280;
  } else {
    int zz = z - 384;
    src = Wo; N = 1024; k0 = (zz >> 4) << 6; n0 = (zz & 15) << 6;
    dsth = Wot; rowoff = 0;
  }
  for (int i = threadIdx.x; i < 1024; i += 256) {
    int r = i >> 4, c4 = i & 15;
    float4 v = *(const float4*)(src + (size_t)(k0 + r) * N + n0 + c4 * 4);
    ld[r][c4 * 4 + 0] = v.x;
    ld[r][c4 * 4 + 1] = v.y;
    ld[r][c4 * 4 + 2] = v.z;
    ld[r][c4 * 4 + 3] = v.w;
  }
  __syncthreads();
  for (int i = threadIdx.x; i < 4096; i += 256) {
    int n = i >> 6, k = i & 63;
    float v = ld[k][n];
    __bf16 hh = (__bf16)v;
    dsth[(size_t)(rowoff + n0 + n) * 1024 + k0 + k] = hh;
    if (dstl)
      dstl[(size_t)(n0 + n) * 1024 + k0 + k] = (__bf16)(v - (float)hh);
  }
}

// ---------------------------------------------------------------------------
// Normalize metric rows (sum of 4 split-K partials); write bf16 hi/lo.
// ---------------------------------------------------------------------------
__global__ __launch_bounds__(256) void normalize_split(
    const float* __restrict__ m0, const float* __restrict__ m1,
    const float* __restrict__ m2, const float* __restrict__ m3,
    __bf16* __restrict__ anh, __bf16* __restrict__ anl,
    __bf16* __restrict__ bnh, __bf16* __restrict__ bnl) {
  const int row = blockIdx.x;
  const int b = row >> 11;
  const int r = row & 2047;
  const int t = threadIdx.x;
  const size_t ix = (size_t)row * 256 + t;
  float v = (m0[ix] + m1[ix]) + (m2[ix] + m3[ix]);
  float ss = v * v;
#pragma unroll
  for (int o = 32; o > 0; o >>= 1) ss += __shfl_xor(ss, o, 64);
  __shared__ float wsum[4];
  if ((t & 63) == 0) wsum[t >> 6] = ss;
  __syncthreads();
  float tot = wsum[0] + wsum[1] + wsum[2] + wsum[3];
  float inv = 1.f / fmaxf(sqrtf(tot), 1e-12f);
  float nv = v * inv;
  __bf16 hh = (__bf16)nv;
  __bf16 ll = (__bf16)(nv - (float)hh);
  size_t o = ((size_t)b * HALF + (r >> 1)) * 256 + t;
  if (r & 1) {
    bnh[o] = hh;
    bnl[o] = ll;
  } else {
    anh[o] = hh;
    anl[o] = ll;
  }
}

// ---------------------------------------------------------------------------
// Fused: reduce 16 argmax partials per row (-> best_b) + stable descending
// bitonic argsort of the 1024 best scores per batch. 512 threads.
// ---------------------------------------------------------------------------
__global__ __launch_bounds__(512) void sort_desc(
    const float* __restrict__ sval, const int* __restrict__ sidx,
    int* __restrict__ best_b, int* __restrict__ order) {
  const int b = blockIdx.x;
  __shared__ float sv[1024];
  __shared__ int si[1024];
  for (int i = threadIdx.x; i < 1024; i += 512) {
    const size_t base = ((size_t)b * HALF + i) * 16;
    float bv = sval[base];
    int bc = sidx[base];
#pragma unroll
    for (int e = 1; e < 16; ++e) {
      float v = sval[base + e];
      int c = sidx[base + e];
      if (v > bv || (v == bv && c < bc)) { bv = v; bc = c; }
    }
    sv[i] = bv;
    si[i] = i;
    best_b[b * HALF + i] = bc;
  }
  __syncthreads();
  for (int k = 2; k <= 1024; k <<= 1) {
    for (int j = k >> 1; j > 0; j >>= 1) {
      for (int t = threadIdx.x; t < 1024; t += 512) {
        int ixj = t ^ j;
        if (ixj > t) {
          bool dir = ((t & k) == 0);
          float va = sv[t], vb = sv[ixj];
          int ia = si[t], ib = si[ixj];
          bool before = (vb > va) || (vb == va && ib < ia);
          if (before == dir) {
            sv[t] = vb; sv[ixj] = va;
            si[t] = ib; si[ixj] = ia;
          }
        }
      }
      __syncthreads();
    }
  }
  for (int i = threadIdx.x; i < 1024; i += 512) order[b * HALF + i] = si[i];
}

// ---------------------------------------------------------------------------
// Parallel greedy selection (exact serial-scan equivalent) + index maps.
// ---------------------------------------------------------------------------
__global__ __launch_bounds__(256) void select_and_index(
    const int* __restrict__ best_b, const int* __restrict__ order,
    int* __restrict__ keep_idx, int* __restrict__ partner,
    int* __restrict__ dst2) {
  const int b = blockIdx.x;
  __shared__ int rankA[HALF];
  __shared__ int minrank[HALF];
  __shared__ int taken[HALF];
  __shared__ int sel_a[RR], sel_b[RR];
  __shared__ int removed[NN];
  __shared__ int src_row[NN];
  __shared__ int tsum[256];
  const int t = threadIdx.x;

  for (int i = t; i < HALF; i += 256) { minrank[i] = 0x7fffffff; taken[i] = 0; }
  for (int i = t; i < NN; i += 256) {
    removed[i] = 0;
    partner[b * NN + i] = -1;
  }
  for (int i = t; i < NM; i += 256) dst2[b * NM + i] = -1;
  __syncthreads();
  int ord[4];
#pragma unroll
  for (int q = 0; q < 4; ++q) {
    int step = t * 4 + q;
    ord[q] = order[b * HALF + step];
    rankA[ord[q]] = step;
  }
  __syncthreads();
#pragma unroll
  for (int q = 0; q < 4; ++q) {
    int a = t * 4 + q;
    atomicMin(&minrank[best_b[b * HALF + a]], rankA[a]);
  }
  __syncthreads();
  for (int i = t; i < HALF; i += 256) {
    int mr = minrank[i];
    if (mr != 0x7fffffff) taken[mr] = 1;
  }
  __syncthreads();
  int c[4];
  int mysum = 0;
#pragma unroll
  for (int q = 0; q < 4; ++q) { c[q] = taken[t * 4 + q]; mysum += c[q]; }
  tsum[t] = mysum;
  __syncthreads();
  for (int off = 1; off < 256; off <<= 1) {
    int v = (t >= off) ? tsum[t - off] : 0;
    __syncthreads();
    tsum[t] += v;
    __syncthreads();
  }
  int run = tsum[t] - mysum;
#pragma unroll
  for (int q = 0; q < 4; ++q) {
    if (c[q] && run < RR) {
      int a = ord[q];
      sel_a[run] = 2 * a;
      sel_b[run] = 2 * best_b[b * HALF + a] + 1;
    }
    run += c[q];
  }
  __syncthreads();
  const int cnt = min(tsum[255], RR);
  if (t >= cnt) { sel_a[t] = sel_a[0]; sel_b[t] = sel_b[0]; }
  __syncthreads();
  {
    int ga = sel_a[t], gb = sel_b[t];
    removed[gb] = 1;
    partner[b * NN + ga] = gb;
  }
  __syncthreads();
  int myc = 0;
#pragma unroll
  for (int q = 0; q < 8; ++q) myc += !removed[8 * t + q];
  tsum[t] = myc;
  __syncthreads();
  for (int off = 1; off < 256; off <<= 1) {
    int v = (t >= off) ? tsum[t - off] : 0;
    __syncthreads();
    tsum[t] += v;
    __syncthreads();
  }
  int pos = tsum[t] - myc;
#pragma unroll
  for (int q = 0; q < 8; ++q) {
    int p = 8 * t + q;
    int sr = -1;
    if (!removed[p]) {
      if (pos < NM) {
        keep_idx[b * NM + pos] = p;
        sr = pos;
      }
      ++pos;
    }
    src_row[p] = sr;
  }
  __syncthreads();
  {
    int sr = src_row[sel_a[t]];
    dst2[b * NM + sr] = sel_b[t];
  }
}

// ---------------------------------------------------------------------------
// Merge -> bf16 x_mb
// ---------------------------------------------------------------------------
__global__ __launch_bounds__(256) void merge_kernel(
    const float* __restrict__ x, const int* __restrict__ keep_idx,
    const int* __restrict__ partner, __bf16* __restrict__ x_mb) {
  const int mrow = blockIdx.x;
  const int b = mrow / NM;
  const int t = mrow % NM;
  const int p = keep_idx[b * NM + t];
  const int pp = partner[b * NN + p];
  const float4* src =
      reinterpret_cast<const float4*>(x + ((size_t)b * NN + p) * DM);
  float4 val = src[threadIdx.x];
  if (pp >= 0) {
    const float4* s2 =
        reinterpret_cast<const float4*>(x + ((size_t)b * NN + pp) * DM);
    float4 v2 = s2[threadIdx.x];
    val.x = 0.5f * (val.x + v2.x);
    val.y = 0.5f * (val.y + v2.y);
    val.z = 0.5f * (val.z + v2.z);
    val.w = 0.5f * (val.w + v2.w);
  }
  union { __bf16 h[4]; uint2 u; } U;
  U.h[0] = (__bf16)val.x;
  U.h[1] = (__bf16)val.y;
  U.h[2] = (__bf16)val.z;
  U.h[3] = (__bf16)val.w;
  ((uint2*)(x_mb + (size_t)mrow * DM))[threadIdx.x] = U.u;
}

// ---------------------------------------------------------------------------
// Flash attention, bf16 MFMA, S^T orientation, fixed-shift softmax,
// split-K over NSPL=4, 8-wave blocks, single-buffer async K/V.
// P routed through padded PER-WAVE LDS (4 ds_write_b64 + 2 ds_read_b128).
// ---------------------------------------------------------------------------
#define LDP 72  // padded P row stride (bf16): 2-way bank alias only (free)

__global__ __launch_bounds__(512) void attn_mfma(
    const __bf16* __restrict__ qbh, const __bf16* __restrict__ kbh,
    const __bf16* __restrict__ vtb, float* __restrict__ pl,
    __bf16* __restrict__ pacc) {
  __shared__ __align__(16) __bf16 Ks[4096];
  __shared__ __align__(16) __bf16 Vs[4096];
  __shared__ __align__(16) __bf16 Pt[8 * 16 * LDP];
  int bid = blockIdx.x;
  const int qt2 = bid % (NM / 32); bid /= (NM / 32);
  const int split = bid % NSPL; bid /= NSPL;
  const int kvh = bid % NKV;
  const int b = bid / NKV;
  const int w = threadIdx.x >> 6;
  const int lane = threadIdx.x & 63;
  const int h = kvh * 4 + (w & 3);
  const int qt = qt2 * 32 + (w >> 2) * 16;
  const int g = lane >> 4;
  const int ml = lane & 15;
  __bf16* Pw = Pt + w * 16 * LDP;

  const __bf16* qrow = qbh + ((size_t)(b * NH + h) * NM + qt + ml) * 64;
  bf16x8 qa0 = *reinterpret_cast<const bf16x8*>(qrow + g * 8);
  bf16x8 qa1 = *reinterpret_cast<const bf16x8*>(qrow + 32 + g * 8);

  f32x4 acc[4];
#pragma unroll
  for (int mt = 0; mt < 4; ++mt) acc[mt] = (f32x4){0.f, 0.f, 0.f, 0.f};
  float lsum = 0.f;

  const __bf16* kp = kbh + (size_t)(b * NKV + kvh) * NM * 64;
  const __bf16* vp = vtb + (size_t)(b * NKV + kvh) * 64 * NM;

  const int jt0 = split * (NT / NSPL);
  for (int jt = jt0; jt < jt0 + NT / NSPL; ++jt) {
    __syncthreads();
    {
      const int c = threadIdx.x;  // 512 chunks each for Ks and Vs
      const int lb = w * 512;
      async16(kp + (size_t)(jt * 64 + ((c >> 7) << 4) + (c & 15)) * 64 +
                  (((c >> 6) & 1) << 5) + (((c >> 4) & 3) << 3),
              &Ks[lb]);
      async16(vp + (size_t)(((c >> 7) << 4) + (c & 15)) * NM + jt * 64 +
                  (((c >> 6) & 1) << 5) + (((c >> 4) & 3) << 3),
              &Vs[lb]);
    }
    __syncthreads();
    f32x4 S[4];
#pragma unroll
    for (int nt = 0; nt < 4; ++nt) {
      bf16x8 k0 = *(const bf16x8*)&Ks[(nt * 128 + lane) * 8];
      bf16x8 k1 = *(const bf16x8*)&Ks[(nt * 128 + 64 + lane) * 8];
      f32x4 s4 = (f32x4){0.f, 0.f, 0.f, 0.f};
      s4 = __builtin_amdgcn_mfma_f32_16x16x32_bf16(k0, qa0, s4, 0, 0, 0);
      s4 = __builtin_amdgcn_mfma_f32_16x16x32_bf16(k1, qa1, s4, 0, 0, 0);
      S[nt] = s4;
    }
#pragma unroll
    for (int nt = 0; nt < 4; ++nt) {
      float p0 = __expf(S[nt][0]);
      float p1 = __expf(S[nt][1]);
      float p2 = __expf(S[nt][2]);
      float p3 = __expf(S[nt][3]);
      lsum += (p0 + p1) + (p2 + p3);
      uint2 u;
      u.x = pk2(p0, p1);
      u.y = pk2(p2, p3);
      *reinterpret_cast<uint2*>(&Pw[ml * LDP + nt * 16 + g * 4]) = u;
    }
    bf16x8 P0 = *(const bf16x8*)&Pw[ml * LDP + g * 8];
    bf16x8 P1 = *(const bf16x8*)&Pw[ml * LDP + 32 + g * 8];
#pragma unroll
    for (int mt = 0; mt < 4; ++mt) {
      bf16x8 v0 = *(const bf16x8*)&Vs[(mt * 128 + lane) * 8];
      bf16x8 v1 = *(const bf16x8*)&Vs[(mt * 128 + 64 + lane) * 8];
      acc[mt] = __builtin_amdgcn_mfma_f32_16x16x32_bf16(v0, P0, acc[mt], 0, 0, 0);
      acc[mt] = __builtin_amdgcn_mfma_f32_16x16x32_bf16(v1, P1, acc[mt], 0, 0, 0);
    }
  }
  lsum += __shfl_xor(lsum, 16, 64);
  lsum += __shfl_xor(lsum, 32, 64);
  const size_t row = (size_t)(b * NH + h) * NM + qt + ml;
  if (g == 0) pl[row * NSPL + split] = lsum;
  __bf16* pa = pacc + (row * NSPL + split) * 64;
#pragma unroll
  for (int mt = 0; mt < 4; ++mt) {
    uint2 u;
    u.x = pk2(acc[mt][0], acc[mt][1]);
    u.y = pk2(acc[mt][2], acc[mt][3]);
    *reinterpret_cast<uint2*>(pa + mt * 16 + g * 4) = u;
  }
}

// ---------------------------------------------------------------------------
// Split-K combine (fixed shift: plain sums) -> bf16 attn_ob
// ---------------------------------------------------------------------------
__global__ __launch_bounds__(256) void attn_combine(
    const float* __restrict__ pl, const __bf16* __restrict__ pacc,
    __bf16* __restrict__ attn_ob) {
  const size_t rid = (size_t)blockIdx.x * 4 + (threadIdx.x >> 6);
  const int d = threadIdx.x & 63;
  float num = 0.f, den = 0.f;
#pragma unroll
  for (int s = 0; s < NSPL; ++s) {
    num += (float)pacc[(rid * NSPL + s) * 64 + d];
    den += pl[rid * NSPL + s];
  }
  float o = num / den;
  const int q = (int)(rid % NM);
  const int h = (int)((rid / NM) % NH);
  const int b = (int)(rid / ((size_t)NM * NH));
  attn_ob[((size_t)(b * NM + q)) * DM + h * 64 + d] = (__bf16)o;
}

// ---------------------------------------------------------------------------
extern "C" void kernel_launch(void* const* d_in, const int* in_sizes, int n_in,
                              void* d_out, int out_size, void* d_ws,
                              size_t ws_size, hipStream_t stream) {
  const float* x = (const float*)d_in[0];
  const float* fc = (const float*)d_in[1];
  const float* Wq = (const float*)d_in[2];
  const float* Wk = (const float*)d_in[3];
  const float* Wv = (const float*)d_in[4];
  const float* Wo = (const float*)d_in[5];
  float* out = (float*)d_out;

  char* ws = (char*)d_ws;
  size_t off = 0;
  auto alloc = [&](size_t bytes) {
    void* p = ws + off;
    off += (bytes + 255) & ~(size_t)255;
    return p;
  };
  float* metric0 = (float*)alloc((size_t)BB * NN * 256 * 4);
  float* metric1 = (float*)alloc((size_t)BB * NN * 256 * 4);
  float* metric2 = (float*)alloc((size_t)BB * NN * 256 * 4);
  float* metric3 = (float*)alloc((size_t)BB * NN * 256 * 4);
  int* best_b = (int*)alloc((size_t)BB * HALF * 4);
  int* order = (int*)alloc((size_t)BB * HALF * 4);
  int* keep_idx = (int*)alloc((size_t)BB * NM * 4);
  int* partner = (int*)alloc((size_t)BB * NN * 4);
  int* dst2 = (int*)alloc((size_t)BB * NM * 4);
  float* sval = (float*)alloc((size_t)BB * HALF * 16 * 4);
  int* sidx = (int*)alloc((size_t)BB * HALF * 16 * 4);
  char* bigreg = (char*)alloc((size_t)30 * 1024 * 1024);
  __bf16* xh = (__bf16*)bigreg;
  __bf16* xl = (__bf16*)(bigreg + (size_t)8704 * 1024);
  __bf16* anh = (__bf16*)bigreg;
  __bf16* anl = (__bf16*)(bigreg + (size_t)1100 * 1024);
  __bf16* bnh = (__bf16*)(bigreg + (size_t)2200 * 1024);
  __bf16* bnl = (__bf16*)(bigreg + (size_t)3300 * 1024);
  __bf16* pacc = (__bf16*)bigreg;
  __bf16* x_mb = (__bf16*)alloc((size_t)BB * NM * DM * 2);
  __bf16* qbh = (__bf16*)alloc((size_t)BB * NH * NM * 64 * 2);
  __bf16* kbh = (__bf16*)alloc((size_t)BB * NKV * NM * 64 * 2);
  __bf16* vtb = (__bf16*)alloc((size_t)BB * NKV * 64 * NM * 2);
  __bf16* attn_ob = (__bf16*)alloc((size_t)BB * NM * DM * 2);
  float* pl = (float*)alloc((size_t)BB * NH * NM * NSPL * 4);
  __bf16* Wqkvt = (__bf16*)alloc((size_t)1536 * DM * 2);
  __bf16* Wktl = (__bf16*)alloc((size_t)256 * DM * 2);
  __bf16* Wot = (__bf16*)alloc((size_t)DM * DM * 2);
  const __bf16* Wkth = Wqkvt + (size_t)1024 * 1024;

  // ---- fused prep: weight transposes + x hi/lo split
  prep_in<<<640 + (BB * NN * DM / 4) / 256, 256, 0, stream>>>(
      Wq, Wk, Wv, Wo, x, Wqkvt, Wktl, Wot, xh, xl);
  // ---- metric = x @ Wk (3-term hi/lo MFMA, 128-row tiles, split-K x4)
  gemm3t<<<dim3(32, 4, 4), 256, 0, stream>>>(xh, xl, Wkth, Wktl, metric0,
                                             metric1, metric2, metric3,
                                             BB * NN, 256, DM);
  normalize_split<<<BB * NN, 256, 0, stream>>>(metric0, metric1, metric2,
                                               metric3, anh, anl, bnh, bnl);
  gemm_scam<<<dim3(8, 16, 2), 256, 0, stream>>>(anh, anl, bnh, bnl, sval,
                                                sidx);
  // ---- fused argmax-reduce + sort
  sort_desc<<<BB, 512, 0, stream>>>(sval, sidx, best_b, order);
  select_and_index<<<BB, 256, 0, stream>>>(best_b, order, keep_idx, partner,
                                           dst2);
  merge_kernel<<<BB * NM, 256, 0, stream>>>(x, keep_idx, partner, x_mb);
  // ---- QKV projection with fused RoPE / head-major repack / V-transpose
  gemm_qkv<<<dim3(28, 24), 256, 0, stream>>>(x_mb, Wqkvt, fc, qbh, kbh, vtb,
                                             BB * NM, 1536, DM);
  // ---- attention (512-thr blocks, split-K x4, LDS-P) + combine
  attn_mfma<<<BB * NKV * NSPL * (NM / 32), 512, 0, stream>>>(qbh, kbh, vtb, pl,
                                                             pacc);
  attn_combine<<<(BB * NH * NM) / 4, 256, 0, stream>>>(pl, pacc, attn_ob);
  // ---- output projection with fused unmerge scatter
  gemm_wo<<<dim3(28, 16), 256, 0, stream>>>(attn_ob, Wot, keep_idx, dst2, out,
                                            BB * NM, DM, DM);
}